// Round 4
// baseline (1562.355 us; speedup 1.0000x reference)
//
#include <hip/hip_runtime.h>
#include <cstdint>

#define NN 50000
#define NE 512000

typedef unsigned short bf16u;

__device__ __forceinline__ bf16u f2bf(float f){
  union { float f; unsigned int u; } v; v.f = f;
  unsigned int r = v.u + 0x7FFFu + ((v.u >> 16) & 1u);
  return (bf16u)(r >> 16);
}
__device__ __forceinline__ float bf2f(bf16u s){
  union { unsigned int u; float f; } v; v.u = ((unsigned int)s) << 16;
  return v.f;
}

// ---------- K0: weight transposes ----------
__global__ void k0_transpose(const float* __restrict__ E_w, const float* __restrict__ ffn2_w,
                             float* __restrict__ WtE, float* __restrict__ W2t){
  int i = blockIdx.x * 256 + threadIdx.x;
  if (i < 64 * 128) { int k = i >> 7, o = i & 127; WtE[i] = E_w[o * 64 + k]; }
  if (i < 128 * 64) { int o = i >> 6, j = i & 63;  W2t[i] = ffn2_w[j * 128 + o]; }
}

// ---------- CSR build ----------
__global__ void k_hist(const int* __restrict__ dst, int* __restrict__ cnt){
  int e = blockIdx.x * 256 + threadIdx.x;
  if (e < NE) atomicAdd(&cnt[dst[e]], 1);
}

#define SCAN_T 1024
#define PER_T 49   // 1024*49 = 50176 >= NN
__global__ __launch_bounds__(SCAN_T) void k_scan(const int* __restrict__ cnt, int* __restrict__ start){
  __shared__ int ls[SCAN_T];
  int t = threadIdx.x;
  int base = t * PER_T;
  int s = 0;
  for (int i = 0; i < PER_T; ++i){ int n = base + i; if (n < NN) s += cnt[n]; }
  ls[t] = s; __syncthreads();
  for (int off = 1; off < SCAN_T; off <<= 1){
    int v = ls[t];
    int add = (t >= off) ? ls[t - off] : 0;
    __syncthreads();
    ls[t] = v + add;
    __syncthreads();
  }
  int run = (t > 0) ? ls[t - 1] : 0;
  for (int i = 0; i < PER_T; ++i){
    int n = base + i;
    if (n < NN){ start[n] = run; run += cnt[n]; }
  }
  if (t == SCAN_T - 1) start[NN] = run;
}

__global__ void k_scatter(const int* __restrict__ dst, int* __restrict__ cursor, int* __restrict__ eidx){
  int e = blockIdx.x * 256 + threadIdx.x;
  if (e < NE){ int p = atomicAdd(&cursor[dst[e]], 1); eidx[p] = e; }
}

// ---------- K1: node QKV (lane = node) ----------
__global__ __launch_bounds__(256) void k1_qkv(const float* __restrict__ x,
    const float* __restrict__ qkv_w, const float* __restrict__ qkv_b,
    float* __restrict__ Q, float* __restrict__ K, float* __restrict__ V){
  int node = blockIdx.x * 256 + threadIdx.x;
  if (node >= NN) return;
  float xr[64];
  const float4* xp = (const float4*)(x + (size_t)node * 64);
#pragma unroll
  for (int c = 0; c < 16; ++c){
    float4 t = xp[c];
    xr[c*4+0]=t.x; xr[c*4+1]=t.y; xr[c*4+2]=t.z; xr[c*4+3]=t.w;
  }
  float* outs[3] = {Q, K, V};
#pragma unroll
  for (int p = 0; p < 3; ++p){
    float* op = outs[p] + (size_t)node * 64;
    for (int o4 = 0; o4 < 16; ++o4){
      float r[4];
#pragma unroll
      for (int j = 0; j < 4; ++j){
        int o = p * 64 + o4 * 4 + j;
        const float* wr = qkv_w + (size_t)o * 64;
        float a = qkv_b[o];
#pragma unroll
        for (int k = 0; k < 64; ++k) a += xr[k] * wr[k];
        r[j] = a;
      }
      float4 st = {r[0], r[1], r[2], r[3]};
      *(float4*)(op + o4 * 4) = st;
    }
  }
}

// ---------- K2: edge pass 1 (lane = edge) — d-blocked, spill-free ----------
// For each 16-wide d-block (== head): ew/eb accumulators over k (e streamed
// from L1), fuse Q/K gather + conn_pre + per-head score. Then conn1 GEMV.
__global__ __launch_bounds__(256) void k2_edge1(
    const float* __restrict__ e, const int* __restrict__ dst, const int* __restrict__ src,
    const float* __restrict__ WtE, const float* __restrict__ E_b,
    const float* __restrict__ Aw, const float* __restrict__ conn1_w, const float* __restrict__ conn1_b,
    const float* __restrict__ Q, const float* __restrict__ K,
    bf16u* __restrict__ cm, float* __restrict__ sexp){
  int edge = blockIdx.x * 256 + threadIdx.x;
  int dn = dst[edge], sn = src[edge];
  const float4* ep = (const float4*)(e + (size_t)edge * 64);
  float cp[64];
  float ex4[4];
#pragma unroll
  for (int db = 0; db < 4; ++db){            // static: cp indices compile-time
    float ew[16], eb[16];
#pragma unroll
    for (int i = 0; i < 16; ++i){ ew[i] = E_b[db*16+i]; eb[i] = E_b[64+db*16+i]; }
    for (int kc = 0; kc < 16; ++kc){         // runtime: bounds code size
      float4 t = ep[kc];
      float ev[4] = {t.x, t.y, t.z, t.w};
      const float* wt = WtE + kc * 4 * 128 + db * 16;   // uniform
#pragma unroll
      for (int j = 0; j < 4; ++j){
#pragma unroll
        for (int i = 0; i < 16; ++i){
          ew[i] += ev[j] * wt[j*128 + i];
          eb[i] += ev[j] * wt[j*128 + 64 + i];
        }
      }
    }
    float s = 0.f;
#pragma unroll
    for (int c4 = 0; c4 < 4; ++c4){
      float4 q4 = *(const float4*)(Q + (size_t)dn * 64 + db*16 + c4*4);
      float4 k4 = *(const float4*)(K + (size_t)sn * 64 + db*16 + c4*4);
      float qv[4] = {q4.x, q4.y, q4.z, q4.w};
      float kv[4] = {k4.x, k4.y, k4.z, k4.w};
#pragma unroll
      for (int j = 0; j < 4; ++j){
        int i = c4*4 + j;
        float c1 = (qv[j] + kv[j]) * ew[i];
        float c2 = copysignf(sqrtf(fabsf(c1)), c1);
        float cpv = fmaxf(c2 + eb[i], 0.f);
        cp[db*16 + i] = cpv;
        s += cpv * Aw[i*4 + db];
      }
    }
    s = fminf(fmaxf(s, -5.f), 5.f);
    ex4[db] = __expf(s);
  }
  float4 sx = {ex4[0], ex4[1], ex4[2], ex4[3]};
  *(float4*)(sexp + (size_t)edge * 4) = sx;
  for (int o4 = 0; o4 < 16; ++o4){           // runtime
    bf16u r[4];
#pragma unroll
    for (int j = 0; j < 4; ++j){
      int o = o4 * 4 + j;
      const float* wr = conn1_w + (size_t)o * 64;
      float a = conn1_b[o];
#pragma unroll
      for (int k = 0; k < 64; ++k) a += cp[k] * wr[k];
      r[j] = f2bf(a);
    }
    ushort4 st = {r[0], r[1], r[2], r[3]};
    *(ushort4*)(cm + (size_t)edge * 64 + o4 * 4) = st;
  }
}

// ---------- K_agg: wave per node, CSR gather (no atomics) ----------
__global__ __launch_bounds__(256) void k_agg(
    const int* __restrict__ start, const int* __restrict__ eidx, const int* __restrict__ srcv,
    const float* __restrict__ sexp, const bf16u* __restrict__ cm, const float* __restrict__ V,
    const float* __restrict__ x, float* __restrict__ hpre){
  int wid = (blockIdx.x * 256 + threadIdx.x) >> 6;
  int lane = threadIdx.x & 63;
  if (wid >= NN) return;
  int s0 = start[wid], s1 = start[wid + 1];
  int h = lane >> 4;
  float ssum = 0.f;
  for (int i = s0; i < s1; ++i){
    int eid = eidx[i];
    ssum += sexp[(size_t)eid * 4 + h];
  }
  float inv = 1.f / (ssum + 1e-16f);
  float acc = 0.f;
  for (int i = s0; i < s1; ++i){
    int eid = eidx[i];
    int sn = srcv[eid];
    float sc = sexp[(size_t)eid * 4 + h] * inv;
    float v  = V[(size_t)sn * 64 + lane];
    float cc = bf2f(cm[(size_t)eid * 64 + lane]);
    acc += (v + cc) * sc;
  }
  hpre[(size_t)wid * 64 + lane] = x[(size_t)wid * 64 + lane] + acc;
}

// ---------- K4: conn path (lane = edge) — in-place LN, spill-free ----------
__global__ __launch_bounds__(256) void k4_conn(
    const float* __restrict__ e, const bf16u* __restrict__ cm,
    const float* __restrict__ g1c, const float* __restrict__ b1c,
    const float* __restrict__ conn2_w, const float* __restrict__ conn2_b,
    const float* __restrict__ g2c, const float* __restrict__ b2c,
    float* __restrict__ out_conn){
  int edge = blockIdx.x * 256 + threadIdx.x;
  float c[64];
  const ushort4* cp4 = (const ushort4*)(cm + (size_t)edge * 64);
#pragma unroll
  for (int q = 0; q < 16; ++q){
    ushort4 t = cp4[q];
    c[q*4+0] = bf2f(t.x); c[q*4+1] = bf2f(t.y); c[q*4+2] = bf2f(t.z); c[q*4+3] = bf2f(t.w);
  }
  float mu = 0.f;
#pragma unroll
  for (int d = 0; d < 64; ++d) mu += c[d];
  mu *= (1.f / 64.f);
  float var = 0.f;
#pragma unroll
  for (int d = 0; d < 64; ++d){ float t = c[d] - mu; var += t * t; }
  var *= (1.f / 64.f);
  float rs = rsqrtf(var + 1e-5f);
#pragma unroll
  for (int d = 0; d < 64; ++d) c[d] = fmaxf((c[d] - mu) * rs * g1c[d] + b1c[d], 0.f);
  // pass 1: stats of r = c@W2c^T + b + e
  float sum = 0.f, sq = 0.f;
  for (int o4 = 0; o4 < 16; ++o4){           // runtime
    float4 e4 = *(const float4*)(e + (size_t)edge * 64 + o4 * 4);
    float evv[4] = {e4.x, e4.y, e4.z, e4.w};
#pragma unroll
    for (int j = 0; j < 4; ++j){
      int o = o4 * 4 + j;
      const float* wr = conn2_w + (size_t)o * 64;
      float a = conn2_b[o];
#pragma unroll
      for (int k = 0; k < 64; ++k) a += c[k] * wr[k];
      float r = a + evv[j];
      sum += r; sq += r * r;
    }
  }
  float mu2 = sum * (1.f / 64.f);
  float var2 = sq * (1.f / 64.f) - mu2 * mu2;
  float rs2 = rsqrtf(fmaxf(var2, 0.f) + 1e-5f);
  // pass 2: recompute, normalize, store
  for (int o4 = 0; o4 < 16; ++o4){           // runtime
    float4 e4 = *(const float4*)(e + (size_t)edge * 64 + o4 * 4);
    float evv[4] = {e4.x, e4.y, e4.z, e4.w};
    float rb[4];
#pragma unroll
    for (int j = 0; j < 4; ++j){
      int o = o4 * 4 + j;
      const float* wr = conn2_w + (size_t)o * 64;
      float a = conn2_b[o];
#pragma unroll
      for (int k = 0; k < 64; ++k) a += c[k] * wr[k];
      float r = a + evv[j];
      rb[j] = (r - mu2) * rs2 * g2c[o] + b2c[o];
    }
    float4 st = {rb[0], rb[1], rb[2], rb[3]};
    *(float4*)(out_conn + (size_t)edge * 64 + o4 * 4) = st;
  }
}

// ---------- K5: node final (lane = node) — streamed LN stats, spill-free ----------
__global__ __launch_bounds__(256) void k5_node(
    const float* __restrict__ hpre,
    const float* __restrict__ g1, const float* __restrict__ b1,
    const float* __restrict__ ffn1_w, const float* __restrict__ ffn1_b,
    const float* __restrict__ W2t, const float* __restrict__ ffn2_b,
    const float* __restrict__ g2, const float* __restrict__ b2,
    float* __restrict__ out_h){
  int node = blockIdx.x * 256 + threadIdx.x;
  if (node >= NN) return;
  const float4* hp = (const float4*)(hpre + (size_t)node * 64);
  // streaming LN1 stats
  float sum = 0.f, sq = 0.f;
#pragma unroll
  for (int q = 0; q < 16; ++q){
    float4 t = hp[q];
    sum += t.x + t.y + t.z + t.w;
    sq  += t.x*t.x + t.y*t.y + t.z*t.z + t.w*t.w;
  }
  float mu = sum * (1.f / 64.f);
  float var = sq * (1.f / 64.f) - mu * mu;
  float rs = rsqrtf(fmaxf(var, 0.f) + 1e-5f);
  float hl[64];
#pragma unroll
  for (int q = 0; q < 16; ++q){
    float4 t = hp[q];                        // L1 hit
    hl[q*4+0] = (t.x - mu) * rs * g1[q*4+0] + b1[q*4+0];
    hl[q*4+1] = (t.y - mu) * rs * g1[q*4+1] + b1[q*4+1];
    hl[q*4+2] = (t.z - mu) * rs * g1[q*4+2] + b1[q*4+2];
    hl[q*4+3] = (t.w - mu) * rs * g1[q*4+3] + b1[q*4+3];
  }
  float oacc[64];
#pragma unroll
  for (int j = 0; j < 64; ++j) oacc[j] = ffn2_b[j];
  for (int o = 0; o < 128; ++o){             // runtime
    const float* wr = ffn1_w + (size_t)o * 64;
    float a = ffn1_b[o];
#pragma unroll
    for (int k = 0; k < 64; ++k) a += hl[k] * wr[k];
    a = fmaxf(a, 0.f);
    const float* w2 = W2t + (size_t)o * 64;
#pragma unroll
    for (int j = 0; j < 64; ++j) oacc[j] += a * w2[j];
  }
  // residual: re-load hpre (hot)
#pragma unroll
  for (int q = 0; q < 16; ++q){
    float4 t = hp[q];
    oacc[q*4+0] += t.x; oacc[q*4+1] += t.y; oacc[q*4+2] += t.z; oacc[q*4+3] += t.w;
  }
  float sum2 = 0.f, sq2 = 0.f;
#pragma unroll
  for (int j = 0; j < 64; ++j){ sum2 += oacc[j]; sq2 += oacc[j]*oacc[j]; }
  float mu2 = sum2 * (1.f / 64.f);
  float var2 = sq2 * (1.f / 64.f) - mu2 * mu2;
  float rs2 = rsqrtf(fmaxf(var2, 0.f) + 1e-5f);
#pragma unroll
  for (int q = 0; q < 16; ++q){
    float rb[4];
#pragma unroll
    for (int j = 0; j < 4; ++j){
      int d = q * 4 + j;
      rb[j] = (oacc[d] - mu2) * rs2 * g2[d] + b2[d];
    }
    float4 st = {rb[0], rb[1], rb[2], rb[3]};
    *(float4*)(out_h + (size_t)node * 64 + q * 4) = st;
  }
}

extern "C" void kernel_launch(void* const* d_in, const int* in_sizes, int n_in,
                              void* d_out, int out_size, void* d_ws, size_t ws_size,
                              hipStream_t stream){
  const float* x       = (const float*)d_in[0];
  const float* e       = (const float*)d_in[1];
  const int*   dst     = (const int*)d_in[2];
  const int*   src     = (const int*)d_in[3];
  const float* qkv_w   = (const float*)d_in[4];
  const float* qkv_b   = (const float*)d_in[5];
  const float* E_w     = (const float*)d_in[6];
  const float* E_b     = (const float*)d_in[7];
  const float* Aw      = (const float*)d_in[8];
  const float* conn1_w = (const float*)d_in[9];
  const float* conn1_b = (const float*)d_in[10];
  const float* conn2_w = (const float*)d_in[11];
  const float* conn2_b = (const float*)d_in[12];
  const float* ffn1_w  = (const float*)d_in[13];
  const float* ffn1_b  = (const float*)d_in[14];
  const float* ffn2_w  = (const float*)d_in[15];
  const float* ffn2_b  = (const float*)d_in[16];
  const float* ln1h_g  = (const float*)d_in[17];
  const float* ln1h_b  = (const float*)d_in[18];
  const float* ln2h_g  = (const float*)d_in[19];
  const float* ln2h_b  = (const float*)d_in[20];
  const float* ln1c_g  = (const float*)d_in[21];
  const float* ln1c_b  = (const float*)d_in[22];
  const float* ln2c_g  = (const float*)d_in[23];
  const float* ln2c_b  = (const float*)d_in[24];

  char* ws = (char*)d_ws;
  size_t off = 0;
  auto alloc = [&](size_t bytes) -> void* {
    void* p = ws + off;
    off += (bytes + 255) & ~(size_t)255;
    return p;
  };
  float* Q     = (float*)alloc((size_t)NN * 64 * 4);
  float* Kq    = (float*)alloc((size_t)NN * 64 * 4);
  float* V     = (float*)alloc((size_t)NN * 64 * 4);
  bf16u* cmb   = (bf16u*)alloc((size_t)NE * 64 * 2);
  float* sexp  = (float*)alloc((size_t)NE * 4 * 4);
  float* hpre  = (float*)alloc((size_t)NN * 64 * 4);
  float* WtE   = (float*)alloc(64 * 128 * 4);
  float* W2t   = (float*)alloc(128 * 64 * 4);
  int*   cnt   = (int*)alloc((size_t)NN * 4);
  int*   startp= (int*)alloc(((size_t)NN + 1) * 4);
  int*   cursor= (int*)alloc((size_t)NN * 4);
  int*   eidx  = (int*)alloc((size_t)NE * 4);

  float* out_h    = (float*)d_out;
  float* out_conn = out_h + (size_t)NN * 64;

  hipMemsetAsync(cnt, 0, (size_t)NN * 4, stream);

  k0_transpose<<<32, 256, 0, stream>>>(E_w, ffn2_w, WtE, W2t);
  k_hist<<<NE / 256, 256, 0, stream>>>(dst, cnt);
  k_scan<<<1, SCAN_T, 0, stream>>>(cnt, startp);
  hipMemcpyAsync(cursor, startp, (size_t)NN * 4, hipMemcpyDeviceToDevice, stream);
  k_scatter<<<NE / 256, 256, 0, stream>>>(dst, cursor, eidx);
  k1_qkv<<<(NN + 255) / 256, 256, 0, stream>>>(x, qkv_w, qkv_b, Q, Kq, V);
  k2_edge1<<<NE / 256, 256, 0, stream>>>(e, dst, src, WtE, E_b, Aw, conn1_w, conn1_b,
                                         Q, Kq, cmb, sexp);
  k_agg<<<(NN * 64 + 255) / 256, 256, 0, stream>>>(startp, eidx, src, sexp, cmb, V, x, hpre);
  k4_conn<<<NE / 256, 256, 0, stream>>>(e, cmb, ln1c_g, ln1c_b, conn2_w, conn2_b,
                                        ln2c_g, ln2c_b, out_conn);
  k5_node<<<(NN + 255) / 256, 256, 0, stream>>>(hpre, ln1h_g, ln1h_b, ffn1_w, ffn1_b,
                                                W2t, ffn2_b, ln2h_g, ln2h_b, out_h);
}

// Round 5
// 846.977 us; speedup vs baseline: 1.8446x; 1.8446x over previous
//
#include <hip/hip_runtime.h>
#include <cstdint>

#define NN 50000
#define NE 512000

typedef unsigned short bf16u;
typedef __attribute__((ext_vector_type(8))) short short8v;
typedef __attribute__((ext_vector_type(4))) float f32x4;

__device__ __forceinline__ bf16u f2bf(float f){
  union { float f; unsigned int u; } v; v.f = f;
  unsigned int r = v.u + 0x7FFFu + ((v.u >> 16) & 1u);
  return (bf16u)(r >> 16);
}
__device__ __forceinline__ float bf2f(bf16u s){
  union { unsigned int u; float f; } v; v.u = ((unsigned int)s) << 16;
  return v.f;
}

// ---------- K0: weight packing ----------
// B-fragment layout for mfma_f32_16x16x32_bf16: lane l supplies
// B[k][n] with n = nf*16 + (l&15), k = ks*32 + (l>>4)*8 + j  (j=0..7).
// BpE: [ks2][nf8][lane64][j8]  from E_w   (Eh = e @ E_w^T: B[k][n]=E_w[n][k])
// Bp1/Bp2: [ks2][nf4][lane64][j8] from conn1_w / conn2_w
// W2t[o*64+j] = ffn2_w[j*128+o]
__global__ void k0_pack(const float* __restrict__ E_w, const float* __restrict__ conn1_w,
                        const float* __restrict__ conn2_w, const float* __restrict__ ffn2_w,
                        bf16u* __restrict__ BpE, bf16u* __restrict__ Bp1,
                        bf16u* __restrict__ Bp2, float* __restrict__ W2t){
  int i = blockIdx.x * 256 + threadIdx.x;   // 0..8191
  if (i < 8192){ int o = i >> 6, j = i & 63; W2t[i] = ffn2_w[j * 128 + o]; }
  if (i < 8192){
    int j = i & 7, l = (i >> 3) & 63, nf = (i >> 9) & 7, ks = i >> 12;
    int n = nf * 16 + (l & 15), k = ks * 32 + ((l >> 4) << 3) + j;
    BpE[i] = f2bf(E_w[n * 64 + k]);
  }
  if (i < 4096){
    int j = i & 7, l = (i >> 3) & 63, nf = (i >> 9) & 3, ks = i >> 11;
    int n = nf * 16 + (l & 15), k = ks * 32 + ((l >> 4) << 3) + j;
    Bp1[i] = f2bf(conn1_w[n * 64 + k]);
    Bp2[i] = f2bf(conn2_w[n * 64 + k]);
  }
}

// ---------- CSR build ----------
__global__ void k_hist(const int* __restrict__ dst, int* __restrict__ cnt){
  int e = blockIdx.x * 256 + threadIdx.x;
  if (e < NE) atomicAdd(&cnt[dst[e]], 1);
}

#define SCAN_T 1024
#define PER_T 49
__global__ __launch_bounds__(SCAN_T) void k_scan(const int* __restrict__ cnt, int* __restrict__ start){
  __shared__ int ls[SCAN_T];
  int t = threadIdx.x;
  int base = t * PER_T;
  int s = 0;
  for (int i = 0; i < PER_T; ++i){ int n = base + i; if (n < NN) s += cnt[n]; }
  ls[t] = s; __syncthreads();
  for (int off = 1; off < SCAN_T; off <<= 1){
    int v = ls[t];
    int add = (t >= off) ? ls[t - off] : 0;
    __syncthreads();
    ls[t] = v + add;
    __syncthreads();
  }
  int run = (t > 0) ? ls[t - 1] : 0;
  for (int i = 0; i < PER_T; ++i){
    int n = base + i;
    if (n < NN){ start[n] = run; run += cnt[n]; }
  }
  if (t == SCAN_T - 1) start[NN] = run;
}

__global__ void k_scatter(const int* __restrict__ dst, int* __restrict__ cursor, int* __restrict__ eidx){
  int e = blockIdx.x * 256 + threadIdx.x;
  if (e < NE){ int p = atomicAdd(&cursor[dst[e]], 1); eidx[p] = e; }
}

// ---------- K1: node QKV (lane = node) ----------
__global__ __launch_bounds__(256) void k1_qkv(const float* __restrict__ x,
    const float* __restrict__ qkv_w, const float* __restrict__ qkv_b,
    float* __restrict__ Q, float* __restrict__ K, float* __restrict__ V){
  int node = blockIdx.x * 256 + threadIdx.x;
  if (node >= NN) return;
  float xr[64];
  const float4* xp = (const float4*)(x + (size_t)node * 64);
#pragma unroll
  for (int c = 0; c < 16; ++c){
    float4 t = xp[c];
    xr[c*4+0]=t.x; xr[c*4+1]=t.y; xr[c*4+2]=t.z; xr[c*4+3]=t.w;
  }
  float* outs[3] = {Q, K, V};
#pragma unroll
  for (int p = 0; p < 3; ++p){
    float* op = outs[p] + (size_t)node * 64;
    for (int o4 = 0; o4 < 16; ++o4){
      float r[4];
#pragma unroll
      for (int j = 0; j < 4; ++j){
        int o = p * 64 + o4 * 4 + j;
        const float* wr = qkv_w + (size_t)o * 64;
        float a = qkv_b[o];
#pragma unroll
        for (int k = 0; k < 64; ++k) a += xr[k] * wr[k];
        r[j] = a;
      }
      float4 st = {r[0], r[1], r[2], r[3]};
      *(float4*)(op + o4 * 4) = st;
    }
  }
}

// ---------- K2: fused edge pass 1 — MFMA ----------
// block = 64 edges, 4 waves. wave w: d-slice [16w,16w+16) for Ew AND Eb.
// Eh MFMA -> pointwise (Q/K gather, sqrt-sign, relu) -> head-w score via
// shfl reduce -> cpre to LDS (stride 72 bf16) -> conn1 MFMA -> cm (bf16).
__global__ __launch_bounds__(256) void k2_edge1(
    const float* __restrict__ e, const int* __restrict__ dst, const int* __restrict__ src,
    const bf16u* __restrict__ BpE, const float* __restrict__ E_b,
    const float* __restrict__ Aw, const bf16u* __restrict__ Bp1, const float* __restrict__ conn1_b,
    const float* __restrict__ Q, const float* __restrict__ K,
    bf16u* __restrict__ cm, float* __restrict__ sexp){
  __shared__ bf16u cpre[64 * 72];
  int tile = blockIdx.x * 64;
  int w = threadIdx.x >> 6, l = threadIdx.x & 63;
  int lg = l >> 4, li = l & 15;
  int dloc = w * 16 + li;

  const short8v* bpe = (const short8v*)BpE;
  short8v BW0 = bpe[(0*8 + w)     * 64 + l];
  short8v BW1 = bpe[(1*8 + w)     * 64 + l];
  short8v BB0 = bpe[(0*8 + 4 + w) * 64 + l];
  short8v BB1 = bpe[(1*8 + 4 + w) * 64 + l];
  const short8v* bp1 = (const short8v*)Bp1;
  short8v B10 = bp1[(0*4 + w) * 64 + l];
  short8v B11 = bp1[(1*4 + w) * 64 + l];

  float eb0 = E_b[dloc], eb1 = E_b[64 + dloc];
  float awv = Aw[li * 4 + w];
  float c1b = conn1_b[dloc];

  f32x4 z = {0.f, 0.f, 0.f, 0.f};
  f32x4 accW[4], accB[4];
#pragma unroll
  for (int mf = 0; mf < 4; ++mf){ accW[mf] = z; accB[mf] = z; }

#pragma unroll
  for (int mf = 0; mf < 4; ++mf){
    const float* ep = e + (size_t)(tile + mf * 16 + li) * 64 + lg * 8;
#pragma unroll
    for (int ks = 0; ks < 2; ++ks){
      float4 a0 = *(const float4*)(ep + ks * 32);
      float4 a1 = *(const float4*)(ep + ks * 32 + 4);
      short8v af;
      af[0]=(short)f2bf(a0.x); af[1]=(short)f2bf(a0.y); af[2]=(short)f2bf(a0.z); af[3]=(short)f2bf(a0.w);
      af[4]=(short)f2bf(a1.x); af[5]=(short)f2bf(a1.y); af[6]=(short)f2bf(a1.z); af[7]=(short)f2bf(a1.w);
      accW[mf] = __builtin_amdgcn_mfma_f32_16x16x32_bf16(af, ks ? BW1 : BW0, accW[mf], 0, 0, 0);
      accB[mf] = __builtin_amdgcn_mfma_f32_16x16x32_bf16(af, ks ? BB1 : BB0, accB[mf], 0, 0, 0);
    }
  }

#pragma unroll
  for (int mf = 0; mf < 4; ++mf){
#pragma unroll
    for (int r = 0; r < 4; ++r){
      int el = mf * 16 + lg * 4 + r;
      int edge = tile + el;
      int dn = dst[edge], sn = src[edge];
      float qv = Q[(size_t)dn * 64 + dloc];
      float kv = K[(size_t)sn * 64 + dloc];
      float ew  = accW[mf][r] + eb0;
      float ebv = accB[mf][r] + eb1;
      float c1 = (qv + kv) * ew;
      float c2 = copysignf(sqrtf(fabsf(c1)), c1);
      float cpv = fmaxf(c2 + ebv, 0.f);
      float s = cpv * awv;
      s += __shfl_xor(s, 1); s += __shfl_xor(s, 2);
      s += __shfl_xor(s, 4); s += __shfl_xor(s, 8);
      if (li == 0){
        float sc = fminf(fmaxf(s, -5.f), 5.f);
        sexp[(size_t)edge * 4 + w] = __expf(sc);
      }
      cpre[el * 72 + dloc] = f2bf(cpv);
    }
  }
  __syncthreads();

#pragma unroll
  for (int mf = 0; mf < 4; ++mf){
    const bf16u* ap = &cpre[(mf * 16 + li) * 72 + lg * 8];
    short8v a20 = *(const short8v*)(ap);
    short8v a21 = *(const short8v*)(ap + 32);
    f32x4 acc = z;
    acc = __builtin_amdgcn_mfma_f32_16x16x32_bf16(a20, B10, acc, 0, 0, 0);
    acc = __builtin_amdgcn_mfma_f32_16x16x32_bf16(a21, B11, acc, 0, 0, 0);
#pragma unroll
    for (int r = 0; r < 4; ++r){
      int edge = tile + mf * 16 + lg * 4 + r;
      cm[(size_t)edge * 64 + dloc] = f2bf(acc[r] + c1b);
    }
  }
}

// ---------- K_agg: wave per node, CSR gather (no atomics) ----------
__global__ __launch_bounds__(256) void k_agg(
    const int* __restrict__ start, const int* __restrict__ eidx, const int* __restrict__ srcv,
    const float* __restrict__ sexp, const bf16u* __restrict__ cm, const float* __restrict__ V,
    const float* __restrict__ x, float* __restrict__ hpre){
  int wid = (blockIdx.x * 256 + threadIdx.x) >> 6;
  int lane = threadIdx.x & 63;
  if (wid >= NN) return;
  int s0 = start[wid], s1 = start[wid + 1];
  int h = lane >> 4;
  float ssum = 0.f;
  for (int i = s0; i < s1; ++i){
    int eid = eidx[i];
    ssum += sexp[(size_t)eid * 4 + h];
  }
  float inv = 1.f / (ssum + 1e-16f);
  float acc = 0.f;
  for (int i = s0; i < s1; ++i){
    int eid = eidx[i];
    int sn = srcv[eid];
    float sc = sexp[(size_t)eid * 4 + h] * inv;
    float v  = V[(size_t)sn * 64 + lane];
    float cc = bf2f(cm[(size_t)eid * 64 + lane]);
    acc += (v + cc) * sc;
  }
  hpre[(size_t)wid * 64 + lane] = x[(size_t)wid * 64 + lane] + acc;
}

// ---------- K4: conn path — MFMA, registers-resident r, cross-wave LN ----------
__global__ __launch_bounds__(256) void k4_conn(
    const float* __restrict__ e, const bf16u* __restrict__ cm,
    const float* __restrict__ g1c, const float* __restrict__ b1c,
    const bf16u* __restrict__ Bp2, const float* __restrict__ conn2_b,
    const float* __restrict__ g2c, const float* __restrict__ b2c,
    float* __restrict__ out_conn){
  __shared__ bf16u cpre[64 * 72];
  __shared__ float reds[64][4];
  __shared__ float redq[64][4];
  int tile = blockIdx.x * 64;
  int t = threadIdx.x;
  // phase 1: LN1c + relu, thread = (edge, quarter-row)
  {
    int el = t >> 2, q = t & 3;
    const bf16u* cr = cm + (size_t)(tile + el) * 64 + q * 16;
    short8v c0 = *(const short8v*)(cr);
    short8v c1 = *(const short8v*)(cr + 8);
    float v[16];
#pragma unroll
    for (int i = 0; i < 8; ++i){ v[i] = bf2f((bf16u)c0[i]); v[8+i] = bf2f((bf16u)c1[i]); }
    float s = 0.f, sq = 0.f;
#pragma unroll
    for (int i = 0; i < 16; ++i){ s += v[i]; sq += v[i]*v[i]; }
    s  += __shfl_xor(s, 1);  s  += __shfl_xor(s, 2);
    sq += __shfl_xor(sq, 1); sq += __shfl_xor(sq, 2);
    float mu = s * (1.f/64.f);
    float var = sq * (1.f/64.f) - mu * mu;
    float rs = rsqrtf(fmaxf(var, 0.f) + 1e-5f);
#pragma unroll
    for (int i = 0; i < 16; ++i){
      int d = q * 16 + i;
      float cn = fmaxf((v[i] - mu) * rs * g1c[d] + b1c[d], 0.f);
      cpre[el * 72 + d] = f2bf(cn);
    }
  }
  __syncthreads();
  int w = t >> 6, l = t & 63;
  int lg = l >> 4, li = l & 15;
  int o = w * 16 + li;
  const short8v* bp2 = (const short8v*)Bp2;
  short8v B20 = bp2[(0*4 + w) * 64 + l];
  short8v B21 = bp2[(1*4 + w) * 64 + l];
  float c2b = conn2_b[o];
  f32x4 z = {0.f, 0.f, 0.f, 0.f};
  float racc[4][4];
#pragma unroll
  for (int mf = 0; mf < 4; ++mf){
    const bf16u* ap = &cpre[(mf * 16 + li) * 72 + lg * 8];
    short8v a0 = *(const short8v*)(ap);
    short8v a1 = *(const short8v*)(ap + 32);
    f32x4 acc = z;
    acc = __builtin_amdgcn_mfma_f32_16x16x32_bf16(a0, B20, acc, 0, 0, 0);
    acc = __builtin_amdgcn_mfma_f32_16x16x32_bf16(a1, B21, acc, 0, 0, 0);
#pragma unroll
    for (int r = 0; r < 4; ++r){
      int el = mf * 16 + lg * 4 + r;
      int edge = tile + el;
      float rv = acc[r] + c2b + e[(size_t)edge * 64 + o];
      racc[mf][r] = rv;
      float s = rv, q2 = rv * rv;
      s  += __shfl_xor(s, 1);  s  += __shfl_xor(s, 2);  s  += __shfl_xor(s, 4);  s  += __shfl_xor(s, 8);
      q2 += __shfl_xor(q2, 1); q2 += __shfl_xor(q2, 2); q2 += __shfl_xor(q2, 4); q2 += __shfl_xor(q2, 8);
      if (li == 0){ reds[el][w] = s; redq[el][w] = q2; }
    }
  }
  __syncthreads();
  float g2v = g2c[o], b2v = b2c[o];
#pragma unroll
  for (int mf = 0; mf < 4; ++mf){
#pragma unroll
    for (int r = 0; r < 4; ++r){
      int el = mf * 16 + lg * 4 + r;
      int edge = tile + el;
      float S = reds[el][0] + reds[el][1] + reds[el][2] + reds[el][3];
      float Qq = redq[el][0] + redq[el][1] + redq[el][2] + redq[el][3];
      float mu2 = S * (1.f/64.f);
      float var2 = Qq * (1.f/64.f) - mu2 * mu2;
      float rs2 = rsqrtf(fmaxf(var2, 0.f) + 1e-5f);
      out_conn[(size_t)edge * 64 + o] = (racc[mf][r] - mu2) * rs2 * g2v + b2v;
    }
  }
}

// ---------- K5: node final (lane = node) ----------
__global__ __launch_bounds__(256) void k5_node(
    const float* __restrict__ hpre,
    const float* __restrict__ g1, const float* __restrict__ b1,
    const float* __restrict__ ffn1_w, const float* __restrict__ ffn1_b,
    const float* __restrict__ W2t, const float* __restrict__ ffn2_b,
    const float* __restrict__ g2, const float* __restrict__ b2,
    float* __restrict__ out_h){
  int node = blockIdx.x * 256 + threadIdx.x;
  if (node >= NN) return;
  const float4* hp = (const float4*)(hpre + (size_t)node * 64);
  float sum = 0.f, sq = 0.f;
#pragma unroll
  for (int q = 0; q < 16; ++q){
    float4 t = hp[q];
    sum += t.x + t.y + t.z + t.w;
    sq  += t.x*t.x + t.y*t.y + t.z*t.z + t.w*t.w;
  }
  float mu = sum * (1.f / 64.f);
  float var = sq * (1.f / 64.f) - mu * mu;
  float rs = rsqrtf(fmaxf(var, 0.f) + 1e-5f);
  float hl[64];
#pragma unroll
  for (int q = 0; q < 16; ++q){
    float4 t = hp[q];
    hl[q*4+0] = (t.x - mu) * rs * g1[q*4+0] + b1[q*4+0];
    hl[q*4+1] = (t.y - mu) * rs * g1[q*4+1] + b1[q*4+1];
    hl[q*4+2] = (t.z - mu) * rs * g1[q*4+2] + b1[q*4+2];
    hl[q*4+3] = (t.w - mu) * rs * g1[q*4+3] + b1[q*4+3];
  }
  float oacc[64];
#pragma unroll
  for (int j = 0; j < 64; ++j) oacc[j] = ffn2_b[j];
  for (int o = 0; o < 128; ++o){
    const float* wr = ffn1_w + (size_t)o * 64;
    float a = ffn1_b[o];
#pragma unroll
    for (int k = 0; k < 64; ++k) a += hl[k] * wr[k];
    a = fmaxf(a, 0.f);
    const float* w2 = W2t + (size_t)o * 64;
#pragma unroll
    for (int j = 0; j < 64; ++j) oacc[j] += a * w2[j];
  }
#pragma unroll
  for (int q = 0; q < 16; ++q){
    float4 t = hp[q];
    oacc[q*4+0] += t.x; oacc[q*4+1] += t.y; oacc[q*4+2] += t.z; oacc[q*4+3] += t.w;
  }
  float sum2 = 0.f, sq2 = 0.f;
#pragma unroll
  for (int j = 0; j < 64; ++j){ sum2 += oacc[j]; sq2 += oacc[j]*oacc[j]; }
  float mu2 = sum2 * (1.f / 64.f);
  float var2 = sq2 * (1.f / 64.f) - mu2 * mu2;
  float rs2 = rsqrtf(fmaxf(var2, 0.f) + 1e-5f);
#pragma unroll
  for (int q = 0; q < 16; ++q){
    float rb[4];
#pragma unroll
    for (int j = 0; j < 4; ++j){
      int d = q * 4 + j;
      rb[j] = (oacc[d] - mu2) * rs2 * g2[d] + b2[d];
    }
    float4 st = {rb[0], rb[1], rb[2], rb[3]};
    *(float4*)(out_h + (size_t)node * 64 + q * 4) = st;
  }
}

extern "C" void kernel_launch(void* const* d_in, const int* in_sizes, int n_in,
                              void* d_out, int out_size, void* d_ws, size_t ws_size,
                              hipStream_t stream){
  const float* x       = (const float*)d_in[0];
  const float* e       = (const float*)d_in[1];
  const int*   dst     = (const int*)d_in[2];
  const int*   src     = (const int*)d_in[3];
  const float* qkv_w   = (const float*)d_in[4];
  const float* qkv_b   = (const float*)d_in[5];
  const float* E_w     = (const float*)d_in[6];
  const float* E_b     = (const float*)d_in[7];
  const float* Aw      = (const float*)d_in[8];
  const float* conn1_w = (const float*)d_in[9];
  const float* conn1_b = (const float*)d_in[10];
  const float* conn2_w = (const float*)d_in[11];
  const float* conn2_b = (const float*)d_in[12];
  const float* ffn1_w  = (const float*)d_in[13];
  const float* ffn1_b  = (const float*)d_in[14];
  const float* ffn2_w  = (const float*)d_in[15];
  const float* ffn2_b  = (const float*)d_in[16];
  const float* ln1h_g  = (const float*)d_in[17];
  const float* ln1h_b  = (const float*)d_in[18];
  const float* ln2h_g  = (const float*)d_in[19];
  const float* ln2h_b  = (const float*)d_in[20];
  const float* ln1c_g  = (const float*)d_in[21];
  const float* ln1c_b  = (const float*)d_in[22];
  const float* ln2c_g  = (const float*)d_in[23];
  const float* ln2c_b  = (const float*)d_in[24];

  char* ws = (char*)d_ws;
  size_t off = 0;
  auto alloc = [&](size_t bytes) -> void* {
    void* p = ws + off;
    off += (bytes + 255) & ~(size_t)255;
    return p;
  };
  float* Q     = (float*)alloc((size_t)NN * 64 * 4);
  float* Kq    = (float*)alloc((size_t)NN * 64 * 4);
  float* V     = (float*)alloc((size_t)NN * 64 * 4);
  bf16u* cmb   = (bf16u*)alloc((size_t)NE * 64 * 2);
  float* sexp  = (float*)alloc((size_t)NE * 4 * 4);
  float* hpre  = (float*)alloc((size_t)NN * 64 * 4);
  float* W2t   = (float*)alloc(128 * 64 * 4);
  bf16u* BpE   = (bf16u*)alloc(8192 * 2);
  bf16u* Bp1   = (bf16u*)alloc(4096 * 2);
  bf16u* Bp2   = (bf16u*)alloc(4096 * 2);
  int*   cnt   = (int*)alloc((size_t)NN * 4);
  int*   startp= (int*)alloc(((size_t)NN + 1) * 4);
  int*   cursor= (int*)alloc((size_t)NN * 4);
  int*   eidx  = (int*)alloc((size_t)NE * 4);

  float* out_h    = (float*)d_out;
  float* out_conn = out_h + (size_t)NN * 64;

  hipMemsetAsync(cnt, 0, (size_t)NN * 4, stream);

  k0_pack<<<32, 256, 0, stream>>>(E_w, conn1_w, conn2_w, ffn2_w, BpE, Bp1, Bp2, W2t);
  k_hist<<<NE / 256, 256, 0, stream>>>(dst, cnt);
  k_scan<<<1, SCAN_T, 0, stream>>>(cnt, startp);
  hipMemcpyAsync(cursor, startp, (size_t)NN * 4, hipMemcpyDeviceToDevice, stream);
  k_scatter<<<NE / 256, 256, 0, stream>>>(dst, cursor, eidx);
  k1_qkv<<<(NN + 255) / 256, 256, 0, stream>>>(x, qkv_w, qkv_b, Q, Kq, V);
  k2_edge1<<<NE / 64, 256, 0, stream>>>(e, dst, src, BpE, E_b, Aw, Bp1, conn1_b,
                                        Q, Kq, cmb, sexp);
  k_agg<<<(NN * 64 + 255) / 256, 256, 0, stream>>>(startp, eidx, src, sexp, cmb, V, x, hpre);
  k4_conn<<<NE / 64, 256, 0, stream>>>(e, cmb, ln1c_g, ln1c_b, Bp2, conn2_b,
                                       ln2c_g, ln2c_b, out_conn);
  k5_node<<<(NN + 255) / 256, 256, 0, stream>>>(hpre, ln1h_g, ln1h_b, ffn1_w, ffn1_b,
                                                W2t, ffn2_b, ln2h_g, ln2h_b, out_h);
}

// Round 6
// 639.535 us; speedup vs baseline: 2.4430x; 1.3244x over previous
//
#include <hip/hip_runtime.h>
#include <cstdint>

#define NN 50000
#define NE 512000

typedef unsigned short bf16u;
typedef __attribute__((ext_vector_type(8))) short short8v;
typedef __attribute__((ext_vector_type(4))) float f32x4;

__device__ __forceinline__ bf16u f2bf(float f){
  union { float f; unsigned int u; } v; v.f = f;
  unsigned int r = v.u + 0x7FFFu + ((v.u >> 16) & 1u);
  return (bf16u)(r >> 16);
}
__device__ __forceinline__ float bf2f(bf16u s){
  union { unsigned int u; float f; } v; v.u = ((unsigned int)s) << 16;
  return v.f;
}

// ---------- K0: weight packing into MFMA B-fragments ----------
// B-frag layout (mfma_f32_16x16x32_bf16): elem [((ks*NF+nf)*64+l)*8+j] =
//   W[n][k],  n = nf*16 + (l&15),  k = ks*32 + ((l>>4)<<3) + j
__global__ void k0_pack(const float* __restrict__ E_w, const float* __restrict__ conn1_w,
                        const float* __restrict__ conn2_w, const float* __restrict__ qkv_w,
                        const float* __restrict__ ffn1_w, const float* __restrict__ ffn2_w,
                        bf16u* __restrict__ BpE, bf16u* __restrict__ Bp1,
                        bf16u* __restrict__ Bp2, bf16u* __restrict__ BpQ,
                        bf16u* __restrict__ BpF1, bf16u* __restrict__ BpF2){
  int i = blockIdx.x * 256 + threadIdx.x;   // 0..12287
  int j = i & 7, l = (i >> 3) & 63;
  int nl = l & 15, kl = (l >> 4) << 3;
  if (i < 8192){   // E_w: (128,64), NF=8, KS=2
    int rest = i >> 9, nf = rest & 7, ks = rest >> 3;
    int n = nf * 16 + nl, k = ks * 32 + kl + j;
    BpE[i] = f2bf(E_w[n * 64 + k]);
  }
  if (i < 4096){   // conn1_w/conn2_w: (64,64), NF=4, KS=2
    int rest = i >> 9, nf = rest & 3, ks = rest >> 2;
    int n = nf * 16 + nl, k = ks * 32 + kl + j;
    Bp1[i] = f2bf(conn1_w[n * 64 + k]);
    Bp2[i] = f2bf(conn2_w[n * 64 + k]);
  }
  if (i < 12288){  // qkv_w: (192,64), NF=12, KS=2
    int rest = i >> 9, nf = rest % 12, ks = rest / 12;
    int n = nf * 16 + nl, k = ks * 32 + kl + j;
    BpQ[i] = f2bf(qkv_w[n * 64 + k]);
  }
  if (i < 8192){   // ffn1_w: (128,64), NF=8, KS=2
    int rest = i >> 9, nf = rest & 7, ks = rest >> 3;
    int n = nf * 16 + nl, k = ks * 32 + kl + j;
    BpF1[i] = f2bf(ffn1_w[n * 64 + k]);
  }
  if (i < 8192){   // ffn2_w: (64,128), NF=4, KS=4
    int rest = i >> 9, nf = rest & 3, ks = rest >> 2;
    int n = nf * 16 + nl, k = ks * 32 + kl + j;
    BpF2[i] = f2bf(ffn2_w[n * 128 + k]);
  }
}

// ---------- CSR build ----------
__global__ void k_hist(const int* __restrict__ dst, int* __restrict__ cnt){
  int e = blockIdx.x * 256 + threadIdx.x;
  if (e < NE) atomicAdd(&cnt[dst[e]], 1);
}

#define SCAN_T 1024
#define PER_T 49
__global__ __launch_bounds__(SCAN_T) void k_scan(const int* __restrict__ cnt, int* __restrict__ start){
  __shared__ int ls[SCAN_T];
  int t = threadIdx.x;
  int base = t * PER_T;
  int s = 0;
  for (int i = 0; i < PER_T; ++i){ int n = base + i; if (n < NN) s += cnt[n]; }
  ls[t] = s; __syncthreads();
  for (int off = 1; off < SCAN_T; off <<= 1){
    int v = ls[t];
    int add = (t >= off) ? ls[t - off] : 0;
    __syncthreads();
    ls[t] = v + add;
    __syncthreads();
  }
  int run = (t > 0) ? ls[t - 1] : 0;
  for (int i = 0; i < PER_T; ++i){
    int n = base + i;
    if (n < NN){ start[n] = run; run += cnt[n]; }
  }
  if (t == SCAN_T - 1) start[NN] = run;
}

__global__ void k_scatter(const int* __restrict__ dst, int* __restrict__ cursor, int* __restrict__ eidx){
  int e = blockIdx.x * 256 + threadIdx.x;
  if (e < NE){ int p = atomicAdd(&cursor[dst[e]], 1); eidx[p] = e; }
}

// ---------- K1: node QKV — MFMA, split-bf16 A ----------
__global__ __launch_bounds__(256) void k1_qkv(const float* __restrict__ x,
    const bf16u* __restrict__ BpQ, const float* __restrict__ qkv_b,
    float* __restrict__ Q, float* __restrict__ K, float* __restrict__ V){
  int tile = blockIdx.x * 64;
  int w = threadIdx.x >> 6, l = threadIdx.x & 63;
  int lg = l >> 4, li = l & 15;
  const short8v* bpq = (const short8v*)BpQ;
  short8v Bq[3][2];
#pragma unroll
  for (int p = 0; p < 3; ++p)
#pragma unroll
    for (int ks = 0; ks < 2; ++ks)
      Bq[p][ks] = bpq[(ks * 12 + p * 4 + w) * 64 + l];
  f32x4 z = {0.f, 0.f, 0.f, 0.f};
  f32x4 acc[3][4];
#pragma unroll
  for (int p = 0; p < 3; ++p)
#pragma unroll
    for (int mf = 0; mf < 4; ++mf) acc[p][mf] = z;
#pragma unroll
  for (int mf = 0; mf < 4; ++mf){
    int row = tile + mf * 16 + li;
    bool g = row < NN;
    const float* xp = x + (size_t)row * 64 + lg * 8;
#pragma unroll
    for (int ks = 0; ks < 2; ++ks){
      float v[8];
      if (g){
        float4 t0 = *(const float4*)(xp + ks * 32);
        float4 t1 = *(const float4*)(xp + ks * 32 + 4);
        v[0]=t0.x; v[1]=t0.y; v[2]=t0.z; v[3]=t0.w;
        v[4]=t1.x; v[5]=t1.y; v[6]=t1.z; v[7]=t1.w;
      } else {
#pragma unroll
        for (int j = 0; j < 8; ++j) v[j] = 0.f;
      }
      short8v hi, lo;
#pragma unroll
      for (int j = 0; j < 8; ++j){
        bf16u h = f2bf(v[j]);
        hi[j] = (short)h;
        lo[j] = (short)f2bf(v[j] - bf2f(h));
      }
#pragma unroll
      for (int p = 0; p < 3; ++p){
        acc[p][mf] = __builtin_amdgcn_mfma_f32_16x16x32_bf16(hi, Bq[p][ks], acc[p][mf], 0, 0, 0);
        acc[p][mf] = __builtin_amdgcn_mfma_f32_16x16x32_bf16(lo, Bq[p][ks], acc[p][mf], 0, 0, 0);
      }
    }
  }
  float bias[3] = {qkv_b[w*16+li], qkv_b[64+w*16+li], qkv_b[128+w*16+li]};
  float* outs[3] = {Q, K, V};
#pragma unroll
  for (int p = 0; p < 3; ++p)
#pragma unroll
    for (int mf = 0; mf < 4; ++mf)
#pragma unroll
      for (int r = 0; r < 4; ++r){
        int row = tile + mf * 16 + lg * 4 + r;
        if (row < NN) outs[p][(size_t)row * 64 + w * 16 + li] = acc[p][mf][r] + bias[p];
      }
}

// ---------- K2: fused edge kernel — Eh + conn_pre + score + conn1 + LN1c + conn2 + LN2c ----------
__global__ __launch_bounds__(256) void k2_edge(
    const float* __restrict__ e, const int* __restrict__ dst, const int* __restrict__ src,
    const bf16u* __restrict__ BpE, const float* __restrict__ E_b,
    const float* __restrict__ Aw, const bf16u* __restrict__ Bp1, const float* __restrict__ conn1_b,
    const float* __restrict__ Q, const float* __restrict__ K,
    const float* __restrict__ g1c, const float* __restrict__ b1c,
    const bf16u* __restrict__ Bp2, const float* __restrict__ conn2_b,
    const float* __restrict__ g2c, const float* __restrict__ b2c,
    bf16u* __restrict__ cm, float* __restrict__ sexp, float* __restrict__ out_conn){
  __shared__ bf16u cpre[64 * 72];
  __shared__ float reds[64][4];
  __shared__ float redq[64][4];
  int tile = blockIdx.x * 64;
  int w = threadIdx.x >> 6, l = threadIdx.x & 63;
  int lg = l >> 4, li = l & 15;
  int dloc = w * 16 + li;

  const short8v* bpe = (const short8v*)BpE;
  short8v BW0 = bpe[(0*8 + w)     * 64 + l];
  short8v BW1 = bpe[(1*8 + w)     * 64 + l];
  short8v BB0 = bpe[(0*8 + 4 + w) * 64 + l];
  short8v BB1 = bpe[(1*8 + 4 + w) * 64 + l];
  const short8v* bp1 = (const short8v*)Bp1;
  short8v B10 = bp1[(0*4 + w) * 64 + l];
  short8v B11 = bp1[(1*4 + w) * 64 + l];
  const short8v* bp2 = (const short8v*)Bp2;
  short8v B20 = bp2[(0*4 + w) * 64 + l];
  short8v B21 = bp2[(1*4 + w) * 64 + l];

  float eb0 = E_b[dloc], eb1 = E_b[64 + dloc];
  float awv = Aw[li * 4 + w];
  float c1b = conn1_b[dloc];

  f32x4 z = {0.f, 0.f, 0.f, 0.f};
  f32x4 accW[4], accB[4];
#pragma unroll
  for (int mf = 0; mf < 4; ++mf){ accW[mf] = z; accB[mf] = z; }

  // --- Eh MFMA ---
#pragma unroll
  for (int mf = 0; mf < 4; ++mf){
    const float* ep = e + (size_t)(tile + mf * 16 + li) * 64 + lg * 8;
#pragma unroll
    for (int ks = 0; ks < 2; ++ks){
      float4 a0 = *(const float4*)(ep + ks * 32);
      float4 a1 = *(const float4*)(ep + ks * 32 + 4);
      short8v af;
      af[0]=(short)f2bf(a0.x); af[1]=(short)f2bf(a0.y); af[2]=(short)f2bf(a0.z); af[3]=(short)f2bf(a0.w);
      af[4]=(short)f2bf(a1.x); af[5]=(short)f2bf(a1.y); af[6]=(short)f2bf(a1.z); af[7]=(short)f2bf(a1.w);
      accW[mf] = __builtin_amdgcn_mfma_f32_16x16x32_bf16(af, ks ? BW1 : BW0, accW[mf], 0, 0, 0);
      accB[mf] = __builtin_amdgcn_mfma_f32_16x16x32_bf16(af, ks ? BB1 : BB0, accB[mf], 0, 0, 0);
    }
  }

  // --- pointwise: conn_pre, score, exp ---
#pragma unroll
  for (int mf = 0; mf < 4; ++mf){
#pragma unroll
    for (int r = 0; r < 4; ++r){
      int el = mf * 16 + lg * 4 + r;
      int edge = tile + el;
      int dn = dst[edge], sn = src[edge];
      float qv = Q[(size_t)dn * 64 + dloc];
      float kv = K[(size_t)sn * 64 + dloc];
      float ew  = accW[mf][r] + eb0;
      float ebv = accB[mf][r] + eb1;
      float c1 = (qv + kv) * ew;
      float c2 = copysignf(sqrtf(fabsf(c1)), c1);
      float cpv = fmaxf(c2 + ebv, 0.f);
      float s = cpv * awv;
      s += __shfl_xor(s, 1); s += __shfl_xor(s, 2);
      s += __shfl_xor(s, 4); s += __shfl_xor(s, 8);
      if (li == 0){
        float sc = fminf(fmaxf(s, -5.f), 5.f);
        sexp[(size_t)edge * 4 + w] = __expf(sc);
      }
      cpre[el * 72 + dloc] = f2bf(cpv);
    }
  }
  __syncthreads();

  // --- conn1 MFMA; keep cmv in regs; store cm; LN1c stats ---
  float cmv[4][4];
#pragma unroll
  for (int mf = 0; mf < 4; ++mf){
    const bf16u* ap = &cpre[(mf * 16 + li) * 72 + lg * 8];
    short8v a0 = *(const short8v*)(ap);
    short8v a1 = *(const short8v*)(ap + 32);
    f32x4 acc = z;
    acc = __builtin_amdgcn_mfma_f32_16x16x32_bf16(a0, B10, acc, 0, 0, 0);
    acc = __builtin_amdgcn_mfma_f32_16x16x32_bf16(a1, B11, acc, 0, 0, 0);
#pragma unroll
    for (int r = 0; r < 4; ++r){
      int el = mf * 16 + lg * 4 + r;
      float v = acc[r] + c1b;
      cmv[mf][r] = v;
      cm[(size_t)(tile + el) * 64 + dloc] = f2bf(v);
      float s = v, q2 = v * v;
      s  += __shfl_xor(s, 1);  s  += __shfl_xor(s, 2);  s  += __shfl_xor(s, 4);  s  += __shfl_xor(s, 8);
      q2 += __shfl_xor(q2, 1); q2 += __shfl_xor(q2, 2); q2 += __shfl_xor(q2, 4); q2 += __shfl_xor(q2, 8);
      if (li == 0){ reds[el][w] = s; redq[el][w] = q2; }
    }
  }
  __syncthreads();

  // --- LN1c normalize + relu -> cpre (overwrite) ---
  float g1v = g1c[dloc], b1v = b1c[dloc];
#pragma unroll
  for (int mf = 0; mf < 4; ++mf){
#pragma unroll
    for (int r = 0; r < 4; ++r){
      int el = mf * 16 + lg * 4 + r;
      float S  = reds[el][0] + reds[el][1] + reds[el][2] + reds[el][3];
      float Qq = redq[el][0] + redq[el][1] + redq[el][2] + redq[el][3];
      float mu = S * (1.f/64.f);
      float var = Qq * (1.f/64.f) - mu * mu;
      float rs = rsqrtf(fmaxf(var, 0.f) + 1e-5f);
      float cn = fmaxf((cmv[mf][r] - mu) * rs * g1v + b1v, 0.f);
      cpre[el * 72 + dloc] = f2bf(cn);
    }
  }
  __syncthreads();

  // --- conn2 MFMA + residual + LN2c stats ---
  float c2b = conn2_b[dloc];
  float racc[4][4];
#pragma unroll
  for (int mf = 0; mf < 4; ++mf){
    const bf16u* ap = &cpre[(mf * 16 + li) * 72 + lg * 8];
    short8v a0 = *(const short8v*)(ap);
    short8v a1 = *(const short8v*)(ap + 32);
    f32x4 acc = z;
    acc = __builtin_amdgcn_mfma_f32_16x16x32_bf16(a0, B20, acc, 0, 0, 0);
    acc = __builtin_amdgcn_mfma_f32_16x16x32_bf16(a1, B21, acc, 0, 0, 0);
#pragma unroll
    for (int r = 0; r < 4; ++r){
      int el = mf * 16 + lg * 4 + r;
      float rv = acc[r] + c2b + e[(size_t)(tile + el) * 64 + dloc];
      racc[mf][r] = rv;
      float s = rv, q2 = rv * rv;
      s  += __shfl_xor(s, 1);  s  += __shfl_xor(s, 2);  s  += __shfl_xor(s, 4);  s  += __shfl_xor(s, 8);
      q2 += __shfl_xor(q2, 1); q2 += __shfl_xor(q2, 2); q2 += __shfl_xor(q2, 4); q2 += __shfl_xor(q2, 8);
      if (li == 0){ reds[el][w] = s; redq[el][w] = q2; }
    }
  }
  __syncthreads();

  // --- LN2c + store ---
  float g2v = g2c[dloc], b2v = b2c[dloc];
#pragma unroll
  for (int mf = 0; mf < 4; ++mf){
#pragma unroll
    for (int r = 0; r < 4; ++r){
      int el = mf * 16 + lg * 4 + r;
      float S  = reds[el][0] + reds[el][1] + reds[el][2] + reds[el][3];
      float Qq = redq[el][0] + redq[el][1] + redq[el][2] + redq[el][3];
      float mu2 = S * (1.f/64.f);
      float var2 = Qq * (1.f/64.f) - mu2 * mu2;
      float rs2 = rsqrtf(fmaxf(var2, 0.f) + 1e-5f);
      out_conn[(size_t)(tile + el) * 64 + dloc] = (racc[mf][r] - mu2) * rs2 * g2v + b2v;
    }
  }
}

// ---------- K_agg: wave per node, CSR gather, single pass ----------
__global__ __launch_bounds__(256) void k_agg(
    const int* __restrict__ start, const int* __restrict__ eidx, const int* __restrict__ srcv,
    const float* __restrict__ sexp, const bf16u* __restrict__ cm, const float* __restrict__ V,
    const float* __restrict__ x, float* __restrict__ hpre){
  int wid = (blockIdx.x * 256 + threadIdx.x) >> 6;
  int lane = threadIdx.x & 63;
  if (wid >= NN) return;
  int s0 = start[wid], s1 = start[wid + 1];
  int h = lane >> 4;
  float num = 0.f, den = 0.f;
  for (int i = s0; i < s1; ++i){
    int eid = eidx[i];
    float sx = sexp[(size_t)eid * 4 + h];
    int sn = srcv[eid];
    float v  = V[(size_t)sn * 64 + lane];
    float cc = bf2f(cm[(size_t)eid * 64 + lane]);
    num += sx * (v + cc);
    den += sx;
  }
  hpre[(size_t)wid * 64 + lane] = x[(size_t)wid * 64 + lane] + num / (den + 1e-16f);
}

// ---------- K5: node final — LN1h + FFN (MFMA) + LN2h ----------
__global__ __launch_bounds__(256) void k5_node(
    const float* __restrict__ hpre,
    const float* __restrict__ g1, const float* __restrict__ b1,
    const bf16u* __restrict__ BpF1, const float* __restrict__ ffn1_b,
    const bf16u* __restrict__ BpF2, const float* __restrict__ ffn2_b,
    const float* __restrict__ g2, const float* __restrict__ b2,
    float* __restrict__ out_h){
  __shared__ bf16u hlhi[64 * 72];
  __shared__ bf16u hllo[64 * 72];
  __shared__ bf16u g1o[64 * 136];
  __shared__ float reds[64][4];
  __shared__ float redq[64][4];
  int tile = blockIdx.x * 64;
  int t = threadIdx.x;
  // phase 1: LN1h (thread = (row, quarter))
  {
    int el = t >> 2, q = t & 3;
    int row = tile + el;
    bool g = row < NN;
    float v[16];
    if (g){
      const float4* hp = (const float4*)(hpre + (size_t)row * 64 + q * 16);
#pragma unroll
      for (int c = 0; c < 4; ++c){
        float4 tv = hp[c];
        v[c*4+0]=tv.x; v[c*4+1]=tv.y; v[c*4+2]=tv.z; v[c*4+3]=tv.w;
      }
    } else {
#pragma unroll
      for (int i = 0; i < 16; ++i) v[i] = 0.f;
    }
    float s = 0.f, sq = 0.f;
#pragma unroll
    for (int i = 0; i < 16; ++i){ s += v[i]; sq += v[i]*v[i]; }
    s  += __shfl_xor(s, 1);  s  += __shfl_xor(s, 2);
    sq += __shfl_xor(sq, 1); sq += __shfl_xor(sq, 2);
    float mu = s * (1.f/64.f);
    float var = sq * (1.f/64.f) - mu * mu;
    float rs = rsqrtf(fmaxf(var, 0.f) + 1e-5f);
#pragma unroll
    for (int i = 0; i < 16; ++i){
      int d = q * 16 + i;
      float hv = (v[i] - mu) * rs * g1[d] + b1[d];
      bf16u hb = f2bf(hv);
      hlhi[el * 72 + d] = hb;
      hllo[el * 72 + d] = f2bf(hv - bf2f(hb));
    }
  }
  __syncthreads();
  int w = t >> 6, l = t & 63;
  int lg = l >> 4, li = l & 15;
  // GEMM1: [64x64] @ [64x128], wave w -> cols {w*16, 64+w*16}
  const short8v* bpf1 = (const short8v*)BpF1;
  short8v B1f[2][2];
#pragma unroll
  for (int f = 0; f < 2; ++f)
#pragma unroll
    for (int ks = 0; ks < 2; ++ks)
      B1f[f][ks] = bpf1[(ks * 8 + f * 4 + w) * 64 + l];
  f32x4 z = {0.f, 0.f, 0.f, 0.f};
  f32x4 acc1[2][4];
#pragma unroll
  for (int f = 0; f < 2; ++f)
#pragma unroll
    for (int mf = 0; mf < 4; ++mf) acc1[f][mf] = z;
#pragma unroll
  for (int mf = 0; mf < 4; ++mf){
#pragma unroll
    for (int ks = 0; ks < 2; ++ks){
      const bf16u* ah = &hlhi[(mf * 16 + li) * 72 + ks * 32 + lg * 8];
      const bf16u* al = &hllo[(mf * 16 + li) * 72 + ks * 32 + lg * 8];
      short8v Ahi = *(const short8v*)ah;
      short8v Alo = *(const short8v*)al;
#pragma unroll
      for (int f = 0; f < 2; ++f){
        acc1[f][mf] = __builtin_amdgcn_mfma_f32_16x16x32_bf16(Ahi, B1f[f][ks], acc1[f][mf], 0, 0, 0);
        acc1[f][mf] = __builtin_amdgcn_mfma_f32_16x16x32_bf16(Alo, B1f[f][ks], acc1[f][mf], 0, 0, 0);
      }
    }
  }
  float fb[2] = {ffn1_b[w*16+li], ffn1_b[64+w*16+li]};
#pragma unroll
  for (int f = 0; f < 2; ++f)
#pragma unroll
    for (int mf = 0; mf < 4; ++mf)
#pragma unroll
      for (int r = 0; r < 4; ++r){
        int rowl = mf * 16 + lg * 4 + r;
        int col = f * 64 + w * 16 + li;
        g1o[rowl * 136 + col] = f2bf(fmaxf(acc1[f][mf][r] + fb[f], 0.f));
      }
  __syncthreads();
  // GEMM2: [64x128] @ [128x64], wave w -> cols w*16..+16
  const short8v* bpf2 = (const short8v*)BpF2;
  short8v B2f[4];
#pragma unroll
  for (int ks = 0; ks < 4; ++ks) B2f[ks] = bpf2[(ks * 4 + w) * 64 + l];
  int o = w * 16 + li;
  float f2b_ = ffn2_b[o];
  float racc[4][4];
#pragma unroll
  for (int mf = 0; mf < 4; ++mf){
    f32x4 acc = z;
#pragma unroll
    for (int ks = 0; ks < 4; ++ks){
      short8v A2 = *(const short8v*)&g1o[(mf * 16 + li) * 136 + ks * 32 + lg * 8];
      acc = __builtin_amdgcn_mfma_f32_16x16x32_bf16(A2, B2f[ks], acc, 0, 0, 0);
    }
#pragma unroll
    for (int r = 0; r < 4; ++r){
      int rowl = mf * 16 + lg * 4 + r;
      int row = tile + rowl;
      float hres = (row < NN) ? hpre[(size_t)row * 64 + o] : 0.f;
      float rv = acc[r] + f2b_ + hres;
      racc[mf][r] = rv;
      float s = rv, q2 = rv * rv;
      s  += __shfl_xor(s, 1);  s  += __shfl_xor(s, 2);  s  += __shfl_xor(s, 4);  s  += __shfl_xor(s, 8);
      q2 += __shfl_xor(q2, 1); q2 += __shfl_xor(q2, 2); q2 += __shfl_xor(q2, 4); q2 += __shfl_xor(q2, 8);
      if (li == 0){ reds[rowl][w] = s; redq[rowl][w] = q2; }
    }
  }
  __syncthreads();
  float g2v = g2[o], b2v = b2[o];
#pragma unroll
  for (int mf = 0; mf < 4; ++mf){
#pragma unroll
    for (int r = 0; r < 4; ++r){
      int rowl = mf * 16 + lg * 4 + r;
      int row = tile + rowl;
      if (row < NN){
        float S  = reds[rowl][0] + reds[rowl][1] + reds[rowl][2] + reds[rowl][3];
        float Qq = redq[rowl][0] + redq[rowl][1] + redq[rowl][2] + redq[rowl][3];
        float mu2 = S * (1.f/64.f);
        float var2 = Qq * (1.f/64.f) - mu2 * mu2;
        float rs2 = rsqrtf(fmaxf(var2, 0.f) + 1e-5f);
        out_h[(size_t)row * 64 + o] = (racc[mf][r] - mu2) * rs2 * g2v + b2v;
      }
    }
  }
}

extern "C" void kernel_launch(void* const* d_in, const int* in_sizes, int n_in,
                              void* d_out, int out_size, void* d_ws, size_t ws_size,
                              hipStream_t stream){
  const float* x       = (const float*)d_in[0];
  const float* e       = (const float*)d_in[1];
  const int*   dst     = (const int*)d_in[2];
  const int*   src     = (const int*)d_in[3];
  const float* qkv_w   = (const float*)d_in[4];
  const float* qkv_b   = (const float*)d_in[5];
  const float* E_w     = (const float*)d_in[6];
  const float* E_b     = (const float*)d_in[7];
  const float* Aw      = (const float*)d_in[8];
  const float* conn1_w = (const float*)d_in[9];
  const float* conn1_b = (const float*)d_in[10];
  const float* conn2_w = (const float*)d_in[11];
  const float* conn2_b = (const float*)d_in[12];
  const float* ffn1_w  = (const float*)d_in[13];
  const float* ffn1_b  = (const float*)d_in[14];
  const float* ffn2_w  = (const float*)d_in[15];
  const float* ffn2_b  = (const float*)d_in[16];
  const float* ln1h_g  = (const float*)d_in[17];
  const float* ln1h_b  = (const float*)d_in[18];
  const float* ln2h_g  = (const float*)d_in[19];
  const float* ln2h_b  = (const float*)d_in[20];
  const float* ln1c_g  = (const float*)d_in[21];
  const float* ln1c_b  = (const float*)d_in[22];
  const float* ln2c_g  = (const float*)d_in[23];
  const float* ln2c_b  = (const float*)d_in[24];

  char* ws = (char*)d_ws;
  size_t off = 0;
  auto alloc = [&](size_t bytes) -> void* {
    void* p = ws + off;
    off += (bytes + 255) & ~(size_t)255;
    return p;
  };
  float* Q     = (float*)alloc((size_t)NN * 64 * 4);
  float* Kq    = (float*)alloc((size_t)NN * 64 * 4);
  float* V     = (float*)alloc((size_t)NN * 64 * 4);
  bf16u* cmb   = (bf16u*)alloc((size_t)NE * 64 * 2);
  float* sexp  = (float*)alloc((size_t)NE * 4 * 4);
  float* hpre  = (float*)alloc((size_t)NN * 64 * 4);
  bf16u* BpE   = (bf16u*)alloc(8192 * 2);
  bf16u* Bp1   = (bf16u*)alloc(4096 * 2);
  bf16u* Bp2   = (bf16u*)alloc(4096 * 2);
  bf16u* BpQ   = (bf16u*)alloc(12288 * 2);
  bf16u* BpF1  = (bf16u*)alloc(8192 * 2);
  bf16u* BpF2  = (bf16u*)alloc(8192 * 2);
  int*   cnt   = (int*)alloc((size_t)NN * 4);
  int*   startp= (int*)alloc(((size_t)NN + 1) * 4);
  int*   cursor= (int*)alloc((size_t)NN * 4);
  int*   eidx  = (int*)alloc((size_t)NE * 4);

  float* out_h    = (float*)d_out;
  float* out_conn = out_h + (size_t)NN * 64;

  hipMemsetAsync(cnt, 0, (size_t)NN * 4, stream);

  k0_pack<<<48, 256, 0, stream>>>(E_w, conn1_w, conn2_w, qkv_w, ffn1_w, ffn2_w,
                                  BpE, Bp1, Bp2, BpQ, BpF1, BpF2);
  k_hist<<<NE / 256, 256, 0, stream>>>(dst, cnt);
  k_scan<<<1, SCAN_T, 0, stream>>>(cnt, startp);
  hipMemcpyAsync(cursor, startp, (size_t)NN * 4, hipMemcpyDeviceToDevice, stream);
  k_scatter<<<NE / 256, 256, 0, stream>>>(dst, cursor, eidx);
  k1_qkv<<<(NN + 63) / 64, 256, 0, stream>>>(x, BpQ, qkv_b, Q, Kq, V);
  k2_edge<<<NE / 64, 256, 0, stream>>>(e, dst, src, BpE, E_b, Aw, Bp1, conn1_b,
                                       Q, Kq, ln1c_g, ln1c_b, Bp2, conn2_b,
                                       ln2c_g, ln2c_b, cmb, sexp, out_conn);
  k_agg<<<(NN * 64 + 255) / 256, 256, 0, stream>>>(startp, eidx, src, sexp, cmb, V, x, hpre);
  k5_node<<<(NN + 63) / 64, 256, 0, stream>>>(hpre, ln1h_g, ln1h_b, BpF1, ffn1_b,
                                              BpF2, ffn2_b, ln2h_g, ln2h_b, out_h);
}

// Round 7
// 639.347 us; speedup vs baseline: 2.4437x; 1.0003x over previous
//
#include <hip/hip_runtime.h>
#include <cstdint>

#define NN 50000
#define NE 512000

typedef unsigned short bf16u;
typedef __attribute__((ext_vector_type(8))) short short8v;
typedef __attribute__((ext_vector_type(4))) float f32x4;

__device__ __forceinline__ bf16u f2bf(float f){
  union { float f; unsigned int u; } v; v.f = f;
  unsigned int r = v.u + 0x7FFFu + ((v.u >> 16) & 1u);
  return (bf16u)(r >> 16);
}
__device__ __forceinline__ float bf2f(bf16u s){
  union { unsigned int u; float f; } v; v.u = ((unsigned int)s) << 16;
  return v.f;
}

// ---------- K0: weight packing into MFMA B-fragments ----------
// B-frag layout (mfma_f32_16x16x32_bf16): elem [((ks*NF+nf)*64+l)*8+j] =
//   W[n][k],  n = nf*16 + (l&15),  k = ks*32 + ((l>>4)<<3) + j
__global__ void k0_pack(const float* __restrict__ E_w, const float* __restrict__ conn1_w,
                        const float* __restrict__ conn2_w, const float* __restrict__ qkv_w,
                        const float* __restrict__ ffn1_w, const float* __restrict__ ffn2_w,
                        bf16u* __restrict__ BpE, bf16u* __restrict__ Bp1,
                        bf16u* __restrict__ Bp2, bf16u* __restrict__ BpQ,
                        bf16u* __restrict__ BpF1, bf16u* __restrict__ BpF2){
  int i = blockIdx.x * 256 + threadIdx.x;   // 0..12287
  int j = i & 7, l = (i >> 3) & 63;
  int nl = l & 15, kl = (l >> 4) << 3;
  if (i < 8192){   // E_w: (128,64), NF=8, KS=2
    int rest = i >> 9, nf = rest & 7, ks = rest >> 3;
    int n = nf * 16 + nl, k = ks * 32 + kl + j;
    BpE[i] = f2bf(E_w[n * 64 + k]);
  }
  if (i < 4096){   // conn1_w/conn2_w: (64,64), NF=4, KS=2
    int rest = i >> 9, nf = rest & 3, ks = rest >> 2;
    int n = nf * 16 + nl, k = ks * 32 + kl + j;
    Bp1[i] = f2bf(conn1_w[n * 64 + k]);
    Bp2[i] = f2bf(conn2_w[n * 64 + k]);
  }
  if (i < 12288){  // qkv_w: (192,64), NF=12, KS=2
    int rest = i >> 9, nf = rest % 12, ks = rest / 12;
    int n = nf * 16 + nl, k = ks * 32 + kl + j;
    BpQ[i] = f2bf(qkv_w[n * 64 + k]);
  }
  if (i < 8192){   // ffn1_w: (128,64), NF=8, KS=2
    int rest = i >> 9, nf = rest & 7, ks = rest >> 3;
    int n = nf * 16 + nl, k = ks * 32 + kl + j;
    BpF1[i] = f2bf(ffn1_w[n * 64 + k]);
  }
  if (i < 8192){   // ffn2_w: (64,128), NF=4, KS=4
    int rest = i >> 9, nf = rest & 3, ks = rest >> 2;
    int n = nf * 16 + nl, k = ks * 32 + kl + j;
    BpF2[i] = f2bf(ffn2_w[n * 128 + k]);
  }
}

// ---------- CSR build ----------
__global__ void k_hist(const int* __restrict__ dst, int* __restrict__ cnt){
  int e = blockIdx.x * 256 + threadIdx.x;
  if (e < NE) atomicAdd(&cnt[dst[e]], 1);
}

#define SCAN_T 1024
#define PER_T 49
__global__ __launch_bounds__(SCAN_T) void k_scan(const int* __restrict__ cnt,
                                                 int* __restrict__ start, int* __restrict__ cursor){
  __shared__ int ls[SCAN_T];
  int t = threadIdx.x;
  int base = t * PER_T;
  int s = 0;
  for (int i = 0; i < PER_T; ++i){ int n = base + i; if (n < NN) s += cnt[n]; }
  ls[t] = s; __syncthreads();
  for (int off = 1; off < SCAN_T; off <<= 1){
    int v = ls[t];
    int add = (t >= off) ? ls[t - off] : 0;
    __syncthreads();
    ls[t] = v + add;
    __syncthreads();
  }
  int run = (t > 0) ? ls[t - 1] : 0;
  for (int i = 0; i < PER_T; ++i){
    int n = base + i;
    if (n < NN){ start[n] = run; cursor[n] = run; run += cnt[n]; }
  }
  if (t == SCAN_T - 1) start[NN] = run;
}

// also emits per-position node id (nid) and source id (sid)
__global__ void k_scatter(const int* __restrict__ dst, const int* __restrict__ src,
                          int* __restrict__ cursor, int* __restrict__ eidx,
                          int* __restrict__ nid, int* __restrict__ sid){
  int e = blockIdx.x * 256 + threadIdx.x;
  if (e < NE){
    int dn = dst[e];
    int p = atomicAdd(&cursor[dn], 1);
    eidx[p] = e;
    nid[p] = dn;
    sid[p] = src[e];
  }
}

// ---------- K1: node QKV — MFMA, split-bf16 A ----------
__global__ __launch_bounds__(256) void k1_qkv(const float* __restrict__ x,
    const bf16u* __restrict__ BpQ, const float* __restrict__ qkv_b,
    float* __restrict__ Q, float* __restrict__ K, float* __restrict__ V){
  int tile = blockIdx.x * 64;
  int w = threadIdx.x >> 6, l = threadIdx.x & 63;
  int lg = l >> 4, li = l & 15;
  const short8v* bpq = (const short8v*)BpQ;
  short8v Bq[3][2];
#pragma unroll
  for (int p = 0; p < 3; ++p)
#pragma unroll
    for (int ks = 0; ks < 2; ++ks)
      Bq[p][ks] = bpq[(ks * 12 + p * 4 + w) * 64 + l];
  f32x4 z = {0.f, 0.f, 0.f, 0.f};
  f32x4 acc[3][4];
#pragma unroll
  for (int p = 0; p < 3; ++p)
#pragma unroll
    for (int mf = 0; mf < 4; ++mf) acc[p][mf] = z;
#pragma unroll
  for (int mf = 0; mf < 4; ++mf){
    int row = tile + mf * 16 + li;
    bool g = row < NN;
    const float* xp = x + (size_t)row * 64 + lg * 8;
#pragma unroll
    for (int ks = 0; ks < 2; ++ks){
      float v[8];
      if (g){
        float4 t0 = *(const float4*)(xp + ks * 32);
        float4 t1 = *(const float4*)(xp + ks * 32 + 4);
        v[0]=t0.x; v[1]=t0.y; v[2]=t0.z; v[3]=t0.w;
        v[4]=t1.x; v[5]=t1.y; v[6]=t1.z; v[7]=t1.w;
      } else {
#pragma unroll
        for (int j = 0; j < 8; ++j) v[j] = 0.f;
      }
      short8v hi, lo;
#pragma unroll
      for (int j = 0; j < 8; ++j){
        bf16u h = f2bf(v[j]);
        hi[j] = (short)h;
        lo[j] = (short)f2bf(v[j] - bf2f(h));
      }
#pragma unroll
      for (int p = 0; p < 3; ++p){
        acc[p][mf] = __builtin_amdgcn_mfma_f32_16x16x32_bf16(hi, Bq[p][ks], acc[p][mf], 0, 0, 0);
        acc[p][mf] = __builtin_amdgcn_mfma_f32_16x16x32_bf16(lo, Bq[p][ks], acc[p][mf], 0, 0, 0);
      }
    }
  }
  float bias[3] = {qkv_b[w*16+li], qkv_b[64+w*16+li], qkv_b[128+w*16+li]};
  float* outs[3] = {Q, K, V};
#pragma unroll
  for (int p = 0; p < 3; ++p)
#pragma unroll
    for (int mf = 0; mf < 4; ++mf)
#pragma unroll
      for (int r = 0; r < 4; ++r){
        int row = tile + mf * 16 + lg * 4 + r;
        if (row < NN) outs[p][(size_t)row * 64 + w * 16 + li] = acc[p][mf][r] + bias[p];
      }
}

// ---------- K2: fused edge kernel, CSR-ordered, VGPR<=64 ----------
// position pos in CSR space; edge id = eidx[pos]; dn=nid[pos]; sn=sid[pos].
// cm/sexp written at pos (sequential for k_agg); out_conn scattered by eid.
__global__ __launch_bounds__(256, 8) void k2_edge(
    const float* __restrict__ e, const int* __restrict__ eidx,
    const int* __restrict__ nid, const int* __restrict__ sid,
    const bf16u* __restrict__ BpE, const float* __restrict__ E_b,
    const float* __restrict__ Aw, const bf16u* __restrict__ Bp1, const float* __restrict__ conn1_b,
    const float* __restrict__ Q, const float* __restrict__ K,
    const float* __restrict__ g1c, const float* __restrict__ b1c,
    const bf16u* __restrict__ Bp2, const float* __restrict__ conn2_b,
    const float* __restrict__ g2c, const float* __restrict__ b2c,
    bf16u* __restrict__ cm, float* __restrict__ sexp, float* __restrict__ out_conn){
  __shared__ bf16u cpre[64 * 72];
  __shared__ float reds[64][4];
  __shared__ float redq[64][4];
  int tile = blockIdx.x * 64;
  int w = threadIdx.x >> 6, l = threadIdx.x & 63;
  int lg = l >> 4, li = l & 15;
  int dloc = w * 16 + li;

  float eb0 = E_b[dloc], eb1 = E_b[64 + dloc];
  float awv = Aw[li * 4 + w];
  f32x4 z = {0.f, 0.f, 0.f, 0.f};

  // --- phase A: per-mf Eh MFMA + pointwise (acc live = 8 regs) ---
  {
    const short8v* bpe = (const short8v*)BpE;
    short8v BW0 = bpe[(0*8 + w)     * 64 + l];
    short8v BW1 = bpe[(1*8 + w)     * 64 + l];
    short8v BB0 = bpe[(0*8 + 4 + w) * 64 + l];
    short8v BB1 = bpe[(1*8 + 4 + w) * 64 + l];
#pragma unroll
    for (int mf = 0; mf < 4; ++mf){
      int eidA = eidx[tile + mf * 16 + li];
      const float* ep = e + (size_t)eidA * 64 + lg * 8;
      f32x4 accW = z, accB = z;
#pragma unroll
      for (int ks = 0; ks < 2; ++ks){
        float4 a0 = *(const float4*)(ep + ks * 32);
        float4 a1 = *(const float4*)(ep + ks * 32 + 4);
        short8v af;
        af[0]=(short)f2bf(a0.x); af[1]=(short)f2bf(a0.y); af[2]=(short)f2bf(a0.z); af[3]=(short)f2bf(a0.w);
        af[4]=(short)f2bf(a1.x); af[5]=(short)f2bf(a1.y); af[6]=(short)f2bf(a1.z); af[7]=(short)f2bf(a1.w);
        accW = __builtin_amdgcn_mfma_f32_16x16x32_bf16(af, ks ? BW1 : BW0, accW, 0, 0, 0);
        accB = __builtin_amdgcn_mfma_f32_16x16x32_bf16(af, ks ? BB1 : BB0, accB, 0, 0, 0);
      }
#pragma unroll
      for (int r = 0; r < 4; ++r){
        int el = mf * 16 + lg * 4 + r;
        int pos = tile + el;
        int dn = nid[pos], sn = sid[pos];
        float qv = Q[(size_t)dn * 64 + dloc];
        float kv = K[(size_t)sn * 64 + dloc];
        float ew  = accW[r] + eb0;
        float ebv = accB[r] + eb1;
        float c1 = (qv + kv) * ew;
        float c2 = copysignf(sqrtf(fabsf(c1)), c1);
        float cpv = fmaxf(c2 + ebv, 0.f);
        float s = cpv * awv;
        s += __shfl_xor(s, 1); s += __shfl_xor(s, 2);
        s += __shfl_xor(s, 4); s += __shfl_xor(s, 8);
        if (li == 0){
          float sc = fminf(fmaxf(s, -5.f), 5.f);
          sexp[(size_t)pos * 4 + w] = __expf(sc);
        }
        cpre[el * 72 + dloc] = f2bf(cpv);
      }
    }
  }
  __syncthreads();

  // --- conn1 MFMA; cmv in regs; store cm (CSR order); LN1c stats ---
  float c1b = conn1_b[dloc];
  float cmv[4][4];
  {
    const short8v* bp1 = (const short8v*)Bp1;
    short8v B10 = bp1[(0*4 + w) * 64 + l];
    short8v B11 = bp1[(1*4 + w) * 64 + l];
#pragma unroll
    for (int mf = 0; mf < 4; ++mf){
      const bf16u* ap = &cpre[(mf * 16 + li) * 72 + lg * 8];
      short8v a0 = *(const short8v*)(ap);
      short8v a1 = *(const short8v*)(ap + 32);
      f32x4 acc = z;
      acc = __builtin_amdgcn_mfma_f32_16x16x32_bf16(a0, B10, acc, 0, 0, 0);
      acc = __builtin_amdgcn_mfma_f32_16x16x32_bf16(a1, B11, acc, 0, 0, 0);
#pragma unroll
      for (int r = 0; r < 4; ++r){
        int el = mf * 16 + lg * 4 + r;
        float v = acc[r] + c1b;
        cmv[mf][r] = v;
        cm[(size_t)(tile + el) * 64 + dloc] = f2bf(v);
        float s = v, q2 = v * v;
        s  += __shfl_xor(s, 1);  s  += __shfl_xor(s, 2);  s  += __shfl_xor(s, 4);  s  += __shfl_xor(s, 8);
        q2 += __shfl_xor(q2, 1); q2 += __shfl_xor(q2, 2); q2 += __shfl_xor(q2, 4); q2 += __shfl_xor(q2, 8);
        if (li == 0){ reds[el][w] = s; redq[el][w] = q2; }
      }
    }
  }
  __syncthreads();

  // --- LN1c normalize + relu -> cpre (overwrite) ---
  float g1v = g1c[dloc], b1v = b1c[dloc];
#pragma unroll
  for (int mf = 0; mf < 4; ++mf){
#pragma unroll
    for (int r = 0; r < 4; ++r){
      int el = mf * 16 + lg * 4 + r;
      float S  = reds[el][0] + reds[el][1] + reds[el][2] + reds[el][3];
      float Qq = redq[el][0] + redq[el][1] + redq[el][2] + redq[el][3];
      float mu = S * (1.f/64.f);
      float var = Qq * (1.f/64.f) - mu * mu;
      float rs = rsqrtf(fmaxf(var, 0.f) + 1e-5f);
      float cn = fmaxf((cmv[mf][r] - mu) * rs * g1v + b1v, 0.f);
      cpre[el * 72 + dloc] = f2bf(cn);
    }
  }
  __syncthreads();

  // --- conn2 MFMA + residual (e gathered by eid) + LN2c stats ---
  float c2b = conn2_b[dloc];
  float racc[4][4];
  {
    const short8v* bp2 = (const short8v*)Bp2;
    short8v B20 = bp2[(0*4 + w) * 64 + l];
    short8v B21 = bp2[(1*4 + w) * 64 + l];
#pragma unroll
    for (int mf = 0; mf < 4; ++mf){
      const bf16u* ap = &cpre[(mf * 16 + li) * 72 + lg * 8];
      short8v a0 = *(const short8v*)(ap);
      short8v a1 = *(const short8v*)(ap + 32);
      f32x4 acc = z;
      acc = __builtin_amdgcn_mfma_f32_16x16x32_bf16(a0, B20, acc, 0, 0, 0);
      acc = __builtin_amdgcn_mfma_f32_16x16x32_bf16(a1, B21, acc, 0, 0, 0);
#pragma unroll
      for (int r = 0; r < 4; ++r){
        int el = mf * 16 + lg * 4 + r;
        int eid = eidx[tile + el];
        float rv = acc[r] + c2b + e[(size_t)eid * 64 + dloc];
        racc[mf][r] = rv;
        float s = rv, q2 = rv * rv;
        s  += __shfl_xor(s, 1);  s  += __shfl_xor(s, 2);  s  += __shfl_xor(s, 4);  s  += __shfl_xor(s, 8);
        q2 += __shfl_xor(q2, 1); q2 += __shfl_xor(q2, 2); q2 += __shfl_xor(q2, 4); q2 += __shfl_xor(q2, 8);
        if (li == 0){ reds[el][w] = s; redq[el][w] = q2; }
      }
    }
  }
  __syncthreads();

  // --- LN2c + scatter store by eid ---
  float g2v = g2c[dloc], b2v = b2c[dloc];
#pragma unroll
  for (int mf = 0; mf < 4; ++mf){
#pragma unroll
    for (int r = 0; r < 4; ++r){
      int el = mf * 16 + lg * 4 + r;
      int eid = eidx[tile + el];
      float S  = reds[el][0] + reds[el][1] + reds[el][2] + reds[el][3];
      float Qq = redq[el][0] + redq[el][1] + redq[el][2] + redq[el][3];
      float mu2 = S * (1.f/64.f);
      float var2 = Qq * (1.f/64.f) - mu2 * mu2;
      float rs2 = rsqrtf(fmaxf(var2, 0.f) + 1e-5f);
      out_conn[(size_t)eid * 64 + dloc] = (racc[mf][r] - mu2) * rs2 * g2v + b2v;
    }
  }
}

// ---------- K_agg: wave per node; cm/sexp/sid sequential, V gathered ----------
__global__ __launch_bounds__(256) void k_agg(
    const int* __restrict__ start, const int* __restrict__ sid,
    const float* __restrict__ sexp, const bf16u* __restrict__ cm, const float* __restrict__ V,
    const float* __restrict__ x, float* __restrict__ hpre){
  int wid = (blockIdx.x * 256 + threadIdx.x) >> 6;
  int lane = threadIdx.x & 63;
  if (wid >= NN) return;
  int s0 = start[wid], s1 = start[wid + 1];
  int h = lane >> 4;
  float num = 0.f, den = 0.f;
  for (int i = s0; i < s1; ++i){
    float sx = sexp[(size_t)i * 4 + h];
    int sn = sid[i];
    float v  = V[(size_t)sn * 64 + lane];
    float cc = bf2f(cm[(size_t)i * 64 + lane]);
    num += sx * (v + cc);
    den += sx;
  }
  hpre[(size_t)wid * 64 + lane] = x[(size_t)wid * 64 + lane] + num / (den + 1e-16f);
}

// ---------- K5: node final — LN1h + FFN (MFMA) + LN2h ----------
__global__ __launch_bounds__(256) void k5_node(
    const float* __restrict__ hpre,
    const float* __restrict__ g1, const float* __restrict__ b1,
    const bf16u* __restrict__ BpF1, const float* __restrict__ ffn1_b,
    const bf16u* __restrict__ BpF2, const float* __restrict__ ffn2_b,
    const float* __restrict__ g2, const float* __restrict__ b2,
    float* __restrict__ out_h){
  __shared__ bf16u hlhi[64 * 72];
  __shared__ bf16u hllo[64 * 72];
  __shared__ bf16u g1o[64 * 136];
  __shared__ float reds[64][4];
  __shared__ float redq[64][4];
  int tile = blockIdx.x * 64;
  int t = threadIdx.x;
  {
    int el = t >> 2, q = t & 3;
    int row = tile + el;
    bool g = row < NN;
    float v[16];
    if (g){
      const float4* hp = (const float4*)(hpre + (size_t)row * 64 + q * 16);
#pragma unroll
      for (int c = 0; c < 4; ++c){
        float4 tv = hp[c];
        v[c*4+0]=tv.x; v[c*4+1]=tv.y; v[c*4+2]=tv.z; v[c*4+3]=tv.w;
      }
    } else {
#pragma unroll
      for (int i = 0; i < 16; ++i) v[i] = 0.f;
    }
    float s = 0.f, sq = 0.f;
#pragma unroll
    for (int i = 0; i < 16; ++i){ s += v[i]; sq += v[i]*v[i]; }
    s  += __shfl_xor(s, 1);  s  += __shfl_xor(s, 2);
    sq += __shfl_xor(sq, 1); sq += __shfl_xor(sq, 2);
    float mu = s * (1.f/64.f);
    float var = sq * (1.f/64.f) - mu * mu;
    float rs = rsqrtf(fmaxf(var, 0.f) + 1e-5f);
#pragma unroll
    for (int i = 0; i < 16; ++i){
      int d = q * 16 + i;
      float hv = (v[i] - mu) * rs * g1[d] + b1[d];
      bf16u hb = f2bf(hv);
      hlhi[el * 72 + d] = hb;
      hllo[el * 72 + d] = f2bf(hv - bf2f(hb));
    }
  }
  __syncthreads();
  int w = t >> 6, l = t & 63;
  int lg = l >> 4, li = l & 15;
  const short8v* bpf1 = (const short8v*)BpF1;
  short8v B1f[2][2];
#pragma unroll
  for (int f = 0; f < 2; ++f)
#pragma unroll
    for (int ks = 0; ks < 2; ++ks)
      B1f[f][ks] = bpf1[(ks * 8 + f * 4 + w) * 64 + l];
  f32x4 z = {0.f, 0.f, 0.f, 0.f};
  f32x4 acc1[2][4];
#pragma unroll
  for (int f = 0; f < 2; ++f)
#pragma unroll
    for (int mf = 0; mf < 4; ++mf) acc1[f][mf] = z;
#pragma unroll
  for (int mf = 0; mf < 4; ++mf){
#pragma unroll
    for (int ks = 0; ks < 2; ++ks){
      const bf16u* ah = &hlhi[(mf * 16 + li) * 72 + ks * 32 + lg * 8];
      const bf16u* al = &hllo[(mf * 16 + li) * 72 + ks * 32 + lg * 8];
      short8v Ahi = *(const short8v*)ah;
      short8v Alo = *(const short8v*)al;
#pragma unroll
      for (int f = 0; f < 2; ++f){
        acc1[f][mf] = __builtin_amdgcn_mfma_f32_16x16x32_bf16(Ahi, B1f[f][ks], acc1[f][mf], 0, 0, 0);
        acc1[f][mf] = __builtin_amdgcn_mfma_f32_16x16x32_bf16(Alo, B1f[f][ks], acc1[f][mf], 0, 0, 0);
      }
    }
  }
  float fb[2] = {ffn1_b[w*16+li], ffn1_b[64+w*16+li]};
#pragma unroll
  for (int f = 0; f < 2; ++f)
#pragma unroll
    for (int mf = 0; mf < 4; ++mf)
#pragma unroll
      for (int r = 0; r < 4; ++r){
        int rowl = mf * 16 + lg * 4 + r;
        int col = f * 64 + w * 16 + li;
        g1o[rowl * 136 + col] = f2bf(fmaxf(acc1[f][mf][r] + fb[f], 0.f));
      }
  __syncthreads();
  const short8v* bpf2 = (const short8v*)BpF2;
  short8v B2f[4];
#pragma unroll
  for (int ks = 0; ks < 4; ++ks) B2f[ks] = bpf2[(ks * 4 + w) * 64 + l];
  int o = w * 16 + li;
  float f2b_ = ffn2_b[o];
  float racc[4][4];
#pragma unroll
  for (int mf = 0; mf < 4; ++mf){
    f32x4 acc = z;
#pragma unroll
    for (int ks = 0; ks < 4; ++ks){
      short8v A2 = *(const short8v*)&g1o[(mf * 16 + li) * 136 + ks * 32 + lg * 8];
      acc = __builtin_amdgcn_mfma_f32_16x16x32_bf16(A2, B2f[ks], acc, 0, 0, 0);
    }
#pragma unroll
    for (int r = 0; r < 4; ++r){
      int rowl = mf * 16 + lg * 4 + r;
      int row = tile + rowl;
      float hres = (row < NN) ? hpre[(size_t)row * 64 + o] : 0.f;
      float rv = acc[r] + f2b_ + hres;
      racc[mf][r] = rv;
      float s = rv, q2 = rv * rv;
      s  += __shfl_xor(s, 1);  s  += __shfl_xor(s, 2);  s  += __shfl_xor(s, 4);  s  += __shfl_xor(s, 8);
      q2 += __shfl_xor(q2, 1); q2 += __shfl_xor(q2, 2); q2 += __shfl_xor(q2, 4); q2 += __shfl_xor(q2, 8);
      if (li == 0){ reds[rowl][w] = s; redq[rowl][w] = q2; }
    }
  }
  __syncthreads();
  float g2v = g2[o], b2v = b2[o];
#pragma unroll
  for (int mf = 0; mf < 4; ++mf){
#pragma unroll
    for (int r = 0; r < 4; ++r){
      int rowl = mf * 16 + lg * 4 + r;
      int row = tile + rowl;
      if (row < NN){
        float S  = reds[rowl][0] + reds[rowl][1] + reds[rowl][2] + reds[rowl][3];
        float Qq = redq[rowl][0] + redq[rowl][1] + redq[rowl][2] + redq[rowl][3];
        float mu2 = S * (1.f/64.f);
        float var2 = Qq * (1.f/64.f) - mu2 * mu2;
        float rs2 = rsqrtf(fmaxf(var2, 0.f) + 1e-5f);
        out_h[(size_t)row * 64 + o] = (racc[mf][r] - mu2) * rs2 * g2v + b2v;
      }
    }
  }
}

extern "C" void kernel_launch(void* const* d_in, const int* in_sizes, int n_in,
                              void* d_out, int out_size, void* d_ws, size_t ws_size,
                              hipStream_t stream){
  const float* x       = (const float*)d_in[0];
  const float* e       = (const float*)d_in[1];
  const int*   dst     = (const int*)d_in[2];
  const int*   src     = (const int*)d_in[3];
  const float* qkv_w   = (const float*)d_in[4];
  const float* qkv_b   = (const float*)d_in[5];
  const float* E_w     = (const float*)d_in[6];
  const float* E_b     = (const float*)d_in[7];
  const float* Aw      = (const float*)d_in[8];
  const float* conn1_w = (const float*)d_in[9];
  const float* conn1_b = (const float*)d_in[10];
  const float* conn2_w = (const float*)d_in[11];
  const float* conn2_b = (const float*)d_in[12];
  const float* ffn1_w  = (const float*)d_in[13];
  const float* ffn1_b  = (const float*)d_in[14];
  const float* ffn2_w  = (const float*)d_in[15];
  const float* ffn2_b  = (const float*)d_in[16];
  const float* ln1h_g  = (const float*)d_in[17];
  const float* ln1h_b  = (const float*)d_in[18];
  const float* ln2h_g  = (const float*)d_in[19];
  const float* ln2h_b  = (const float*)d_in[20];
  const float* ln1c_g  = (const float*)d_in[21];
  const float* ln1c_b  = (const float*)d_in[22];
  const float* ln2c_g  = (const float*)d_in[23];
  const float* ln2c_b  = (const float*)d_in[24];

  char* ws = (char*)d_ws;
  size_t off = 0;
  auto alloc = [&](size_t bytes) -> void* {
    void* p = ws + off;
    off += (bytes + 255) & ~(size_t)255;
    return p;
  };
  float* Q     = (float*)alloc((size_t)NN * 64 * 4);
  float* Kq    = (float*)alloc((size_t)NN * 64 * 4);
  float* V     = (float*)alloc((size_t)NN * 64 * 4);
  bf16u* cmb   = (bf16u*)alloc((size_t)NE * 64 * 2);
  float* sexp  = (float*)alloc((size_t)NE * 4 * 4);
  float* hpre  = (float*)alloc((size_t)NN * 64 * 4);
  bf16u* BpE   = (bf16u*)alloc(8192 * 2);
  bf16u* Bp1   = (bf16u*)alloc(4096 * 2);
  bf16u* Bp2   = (bf16u*)alloc(4096 * 2);
  bf16u* BpQ   = (bf16u*)alloc(12288 * 2);
  bf16u* BpF1  = (bf16u*)alloc(8192 * 2);
  bf16u* BpF2  = (bf16u*)alloc(8192 * 2);
  int*   cnt   = (int*)alloc((size_t)NN * 4);
  int*   startp= (int*)alloc(((size_t)NN + 1) * 4);
  int*   cursor= (int*)alloc((size_t)NN * 4);
  int*   eidx  = (int*)alloc((size_t)NE * 4);
  int*   nid   = (int*)alloc((size_t)NE * 4);
  int*   sid   = (int*)alloc((size_t)NE * 4);

  float* out_h    = (float*)d_out;
  float* out_conn = out_h + (size_t)NN * 64;

  hipMemsetAsync(cnt, 0, (size_t)NN * 4, stream);

  k0_pack<<<48, 256, 0, stream>>>(E_w, conn1_w, conn2_w, qkv_w, ffn1_w, ffn2_w,
                                  BpE, Bp1, Bp2, BpQ, BpF1, BpF2);
  k_hist<<<NE / 256, 256, 0, stream>>>(dst, cnt);
  k_scan<<<1, SCAN_T, 0, stream>>>(cnt, startp, cursor);
  k_scatter<<<NE / 256, 256, 0, stream>>>(dst, src, cursor, eidx, nid, sid);
  k1_qkv<<<(NN + 63) / 64, 256, 0, stream>>>(x, BpQ, qkv_b, Q, Kq, V);
  k2_edge<<<NE / 64, 256, 0, stream>>>(e, eidx, nid, sid, BpE, E_b, Aw, Bp1, conn1_b,
                                       Q, Kq, ln1c_g, ln1c_b, Bp2, conn2_b,
                                       ln2c_g, ln2c_b, cmb, sexp, out_conn);
  k_agg<<<(NN * 64 + 255) / 256, 256, 0, stream>>>(startp, sid, sexp, cmb, V, x, hpre);
  k5_node<<<(NN + 63) / 64, 256, 0, stream>>>(hpre, ln1h_g, ln1h_b, BpF1, ffn1_b,
                                              BpF2, ffn2_b, ln2h_g, ln2h_b, out_h);
}

// Round 8
// 637.869 us; speedup vs baseline: 2.4493x; 1.0023x over previous
//
#include <hip/hip_runtime.h>
#include <cstdint>

#define NN 50000
#define NE 512000

typedef unsigned short bf16u;
typedef __attribute__((ext_vector_type(8))) short short8v;
typedef __attribute__((ext_vector_type(4))) float f32x4;

__device__ __forceinline__ bf16u f2bf(float f){
  union { float f; unsigned int u; } v; v.f = f;
  unsigned int r = v.u + 0x7FFFu + ((v.u >> 16) & 1u);
  return (bf16u)(r >> 16);
}
__device__ __forceinline__ float bf2f(bf16u s){
  union { unsigned int u; float f; } v; v.u = ((unsigned int)s) << 16;
  return v.f;
}

// ---------- K0: weight packing into MFMA B-fragments ----------
// B-frag layout (mfma_f32_16x16x32_bf16): elem [((ks*NF+nf)*64+l)*8+j] =
//   W[n][k],  n = nf*16 + (l&15),  k = ks*32 + ((l>>4)<<3) + j
__global__ void k0_pack(const float* __restrict__ E_w, const float* __restrict__ conn1_w,
                        const float* __restrict__ conn2_w, const float* __restrict__ qkv_w,
                        const float* __restrict__ ffn1_w, const float* __restrict__ ffn2_w,
                        bf16u* __restrict__ BpE, bf16u* __restrict__ Bp1,
                        bf16u* __restrict__ Bp2, bf16u* __restrict__ BpQ,
                        bf16u* __restrict__ BpF1, bf16u* __restrict__ BpF2){
  int i = blockIdx.x * 256 + threadIdx.x;   // 0..12287
  int j = i & 7, l = (i >> 3) & 63;
  int nl = l & 15, kl = (l >> 4) << 3;
  if (i < 8192){   // E_w: (128,64), NF=8, KS=2
    int rest = i >> 9, nf = rest & 7, ks = rest >> 3;
    int n = nf * 16 + nl, k = ks * 32 + kl + j;
    BpE[i] = f2bf(E_w[n * 64 + k]);
  }
  if (i < 4096){   // conn1_w/conn2_w: (64,64), NF=4, KS=2
    int rest = i >> 9, nf = rest & 3, ks = rest >> 2;
    int n = nf * 16 + nl, k = ks * 32 + kl + j;
    Bp1[i] = f2bf(conn1_w[n * 64 + k]);
    Bp2[i] = f2bf(conn2_w[n * 64 + k]);
  }
  if (i < 12288){  // qkv_w: (192,64), NF=12, KS=2
    int rest = i >> 9, nf = rest % 12, ks = rest / 12;
    int n = nf * 16 + nl, k = ks * 32 + kl + j;
    BpQ[i] = f2bf(qkv_w[n * 64 + k]);
  }
  if (i < 8192){   // ffn1_w: (128,64), NF=8, KS=2
    int rest = i >> 9, nf = rest & 7, ks = rest >> 3;
    int n = nf * 16 + nl, k = ks * 32 + kl + j;
    BpF1[i] = f2bf(ffn1_w[n * 64 + k]);
  }
  if (i < 8192){   // ffn2_w: (64,128), NF=4, KS=4
    int rest = i >> 9, nf = rest & 3, ks = rest >> 2;
    int n = nf * 16 + nl, k = ks * 32 + kl + j;
    BpF2[i] = f2bf(ffn2_w[n * 128 + k]);
  }
}

// ---------- CSR build ----------
__global__ void k_hist(const int* __restrict__ dst, int* __restrict__ cnt){
  int e = blockIdx.x * 256 + threadIdx.x;
  if (e < NE) atomicAdd(&cnt[dst[e]], 1);
}

#define SCAN_T 1024
#define PER_T 49
__global__ __launch_bounds__(SCAN_T) void k_scan(const int* __restrict__ cnt,
                                                 int* __restrict__ start, int* __restrict__ cursor){
  __shared__ int ls[SCAN_T];
  int t = threadIdx.x;
  int base = t * PER_T;
  int s = 0;
  for (int i = 0; i < PER_T; ++i){ int n = base + i; if (n < NN) s += cnt[n]; }
  ls[t] = s; __syncthreads();
  for (int off = 1; off < SCAN_T; off <<= 1){
    int v = ls[t];
    int add = (t >= off) ? ls[t - off] : 0;
    __syncthreads();
    ls[t] = v + add;
    __syncthreads();
  }
  int run = (t > 0) ? ls[t - 1] : 0;
  for (int i = 0; i < PER_T; ++i){
    int n = base + i;
    if (n < NN){ start[n] = run; cursor[n] = run; run += cnt[n]; }
  }
  if (t == SCAN_T - 1) start[NN] = run;
}

__global__ void k_scatter(const int* __restrict__ dst, const int* __restrict__ src,
                          int* __restrict__ cursor, int* __restrict__ eidx,
                          int* __restrict__ nid, int* __restrict__ sid){
  int e = blockIdx.x * 256 + threadIdx.x;
  if (e < NE){
    int dn = dst[e];
    int p = atomicAdd(&cursor[dn], 1);
    eidx[p] = e;
    nid[p] = dn;
    sid[p] = src[e];
  }
}

// ---------- K1: node QKV — MFMA, split-bf16 A ----------
__global__ __launch_bounds__(256) void k1_qkv(const float* __restrict__ x,
    const bf16u* __restrict__ BpQ, const float* __restrict__ qkv_b,
    float* __restrict__ Q, float* __restrict__ K, float* __restrict__ V){
  int tile = blockIdx.x * 64;
  int w = threadIdx.x >> 6, l = threadIdx.x & 63;
  int lg = l >> 4, li = l & 15;
  const short8v* bpq = (const short8v*)BpQ;
  short8v Bq[3][2];
#pragma unroll
  for (int p = 0; p < 3; ++p)
#pragma unroll
    for (int ks = 0; ks < 2; ++ks)
      Bq[p][ks] = bpq[(ks * 12 + p * 4 + w) * 64 + l];
  f32x4 z = {0.f, 0.f, 0.f, 0.f};
  f32x4 acc[3][4];
#pragma unroll
  for (int p = 0; p < 3; ++p)
#pragma unroll
    for (int mf = 0; mf < 4; ++mf) acc[p][mf] = z;
#pragma unroll
  for (int mf = 0; mf < 4; ++mf){
    int row = tile + mf * 16 + li;
    bool g = row < NN;
    const float* xp = x + (size_t)row * 64 + lg * 8;
#pragma unroll
    for (int ks = 0; ks < 2; ++ks){
      float v[8];
      if (g){
        float4 t0 = *(const float4*)(xp + ks * 32);
        float4 t1 = *(const float4*)(xp + ks * 32 + 4);
        v[0]=t0.x; v[1]=t0.y; v[2]=t0.z; v[3]=t0.w;
        v[4]=t1.x; v[5]=t1.y; v[6]=t1.z; v[7]=t1.w;
      } else {
#pragma unroll
        for (int j = 0; j < 8; ++j) v[j] = 0.f;
      }
      short8v hi, lo;
#pragma unroll
      for (int j = 0; j < 8; ++j){
        bf16u h = f2bf(v[j]);
        hi[j] = (short)h;
        lo[j] = (short)f2bf(v[j] - bf2f(h));
      }
#pragma unroll
      for (int p = 0; p < 3; ++p){
        acc[p][mf] = __builtin_amdgcn_mfma_f32_16x16x32_bf16(hi, Bq[p][ks], acc[p][mf], 0, 0, 0);
        acc[p][mf] = __builtin_amdgcn_mfma_f32_16x16x32_bf16(lo, Bq[p][ks], acc[p][mf], 0, 0, 0);
      }
    }
  }
  float bias[3] = {qkv_b[w*16+li], qkv_b[64+w*16+li], qkv_b[128+w*16+li]};
  float* outs[3] = {Q, K, V};
#pragma unroll
  for (int p = 0; p < 3; ++p)
#pragma unroll
    for (int mf = 0; mf < 4; ++mf)
#pragma unroll
      for (int r = 0; r < 4; ++r){
        int row = tile + mf * 16 + lg * 4 + r;
        if (row < NN) outs[p][(size_t)row * 64 + w * 16 + li] = acc[p][mf][r] + bias[p];
      }
}

// ---------- K2: fused edge kernel, CSR-ordered, cmv offloaded to LDS ----------
__global__ __launch_bounds__(256, 8) void k2_edge(
    const float* __restrict__ e, const int* __restrict__ eidx,
    const int* __restrict__ nid, const int* __restrict__ sid,
    const bf16u* __restrict__ BpE, const float* __restrict__ E_b,
    const float* __restrict__ Aw, const bf16u* __restrict__ Bp1, const float* __restrict__ conn1_b,
    const float* __restrict__ Q, const float* __restrict__ K,
    const float* __restrict__ g1c, const float* __restrict__ b1c,
    const bf16u* __restrict__ Bp2, const float* __restrict__ conn2_b,
    const float* __restrict__ g2c, const float* __restrict__ b2c,
    bf16u* __restrict__ cm, float* __restrict__ sexp, float* __restrict__ out_conn){
  __shared__ bf16u cpre[64 * 72];
  __shared__ bf16u cmid[64 * 72];
  __shared__ float reds[64][4];
  __shared__ float redq[64][4];
  int tile = blockIdx.x * 64;
  int w = threadIdx.x >> 6, l = threadIdx.x & 63;
  int lg = l >> 4, li = l & 15;
  int dloc = w * 16 + li;

  float eb0 = E_b[dloc], eb1 = E_b[64 + dloc];
  float awv = Aw[li * 4 + w];
  f32x4 z = {0.f, 0.f, 0.f, 0.f};

  // --- phase A: per-mf Eh MFMA + pointwise ---
  {
    const short8v* bpe = (const short8v*)BpE;
    short8v BW0 = bpe[(0*8 + w)     * 64 + l];
    short8v BW1 = bpe[(1*8 + w)     * 64 + l];
    short8v BB0 = bpe[(0*8 + 4 + w) * 64 + l];
    short8v BB1 = bpe[(1*8 + 4 + w) * 64 + l];
#pragma unroll
    for (int mf = 0; mf < 4; ++mf){
      int eidA = eidx[tile + mf * 16 + li];
      const float* ep = e + (size_t)eidA * 64 + lg * 8;
      f32x4 accW = z, accB = z;
#pragma unroll
      for (int ks = 0; ks < 2; ++ks){
        float4 a0 = *(const float4*)(ep + ks * 32);
        float4 a1 = *(const float4*)(ep + ks * 32 + 4);
        short8v af;
        af[0]=(short)f2bf(a0.x); af[1]=(short)f2bf(a0.y); af[2]=(short)f2bf(a0.z); af[3]=(short)f2bf(a0.w);
        af[4]=(short)f2bf(a1.x); af[5]=(short)f2bf(a1.y); af[6]=(short)f2bf(a1.z); af[7]=(short)f2bf(a1.w);
        accW = __builtin_amdgcn_mfma_f32_16x16x32_bf16(af, ks ? BW1 : BW0, accW, 0, 0, 0);
        accB = __builtin_amdgcn_mfma_f32_16x16x32_bf16(af, ks ? BB1 : BB0, accB, 0, 0, 0);
      }
#pragma unroll
      for (int r = 0; r < 4; ++r){
        int el = mf * 16 + lg * 4 + r;
        int pos = tile + el;
        int dn = nid[pos], sn = sid[pos];
        float qv = Q[(size_t)dn * 64 + dloc];
        float kv = K[(size_t)sn * 64 + dloc];
        float ew  = accW[r] + eb0;
        float ebv = accB[r] + eb1;
        float c1 = (qv + kv) * ew;
        float c2 = copysignf(sqrtf(fabsf(c1)), c1);
        float cpv = fmaxf(c2 + ebv, 0.f);
        float s = cpv * awv;
        s += __shfl_xor(s, 1); s += __shfl_xor(s, 2);
        s += __shfl_xor(s, 4); s += __shfl_xor(s, 8);
        if (li == 0){
          float sc = fminf(fmaxf(s, -5.f), 5.f);
          sexp[(size_t)pos * 4 + w] = __expf(sc);
        }
        cpre[el * 72 + dloc] = f2bf(cpv);
      }
    }
  }
  __syncthreads();

  // --- phase B: conn1 MFMA; store cm global + cmid LDS; LN1c stats (f32) ---
  float c1b = conn1_b[dloc];
  {
    const short8v* bp1 = (const short8v*)Bp1;
    short8v B10 = bp1[(0*4 + w) * 64 + l];
    short8v B11 = bp1[(1*4 + w) * 64 + l];
#pragma unroll
    for (int mf = 0; mf < 4; ++mf){
      const bf16u* ap = &cpre[(mf * 16 + li) * 72 + lg * 8];
      short8v a0 = *(const short8v*)(ap);
      short8v a1 = *(const short8v*)(ap + 32);
      f32x4 acc = z;
      acc = __builtin_amdgcn_mfma_f32_16x16x32_bf16(a0, B10, acc, 0, 0, 0);
      acc = __builtin_amdgcn_mfma_f32_16x16x32_bf16(a1, B11, acc, 0, 0, 0);
#pragma unroll
      for (int r = 0; r < 4; ++r){
        int el = mf * 16 + lg * 4 + r;
        float v = acc[r] + c1b;
        bf16u vb = f2bf(v);
        cm[(size_t)(tile + el) * 64 + dloc] = vb;
        cmid[el * 72 + dloc] = vb;
        float s = v, q2 = v * v;
        s  += __shfl_xor(s, 1);  s  += __shfl_xor(s, 2);  s  += __shfl_xor(s, 4);  s  += __shfl_xor(s, 8);
        q2 += __shfl_xor(q2, 1); q2 += __shfl_xor(q2, 2); q2 += __shfl_xor(q2, 4); q2 += __shfl_xor(q2, 8);
        if (li == 0){ reds[el][w] = s; redq[el][w] = q2; }
      }
    }
  }
  __syncthreads();

  // --- phase C: LN1c normalize + relu -> cpre (overwrite) ---
  float g1v = g1c[dloc], b1v = b1c[dloc];
#pragma unroll
  for (int mf = 0; mf < 4; ++mf){
#pragma unroll
    for (int r = 0; r < 4; ++r){
      int el = mf * 16 + lg * 4 + r;
      float S  = reds[el][0] + reds[el][1] + reds[el][2] + reds[el][3];
      float Qq = redq[el][0] + redq[el][1] + redq[el][2] + redq[el][3];
      float mu = S * (1.f/64.f);
      float var = Qq * (1.f/64.f) - mu * mu;
      float rs = rsqrtf(fmaxf(var, 0.f) + 1e-5f);
      float cv = bf2f(cmid[el * 72 + dloc]);
      float cn = fmaxf((cv - mu) * rs * g1v + b1v, 0.f);
      cpre[el * 72 + dloc] = f2bf(cn);
    }
  }
  __syncthreads();

  // --- phase D: conn2 MFMA + residual + LN2c stats (racc in regs) ---
  float c2b = conn2_b[dloc];
  float racc[4][4];
  {
    const short8v* bp2 = (const short8v*)Bp2;
    short8v B20 = bp2[(0*4 + w) * 64 + l];
    short8v B21 = bp2[(1*4 + w) * 64 + l];
#pragma unroll
    for (int mf = 0; mf < 4; ++mf){
      const bf16u* ap = &cpre[(mf * 16 + li) * 72 + lg * 8];
      short8v a0 = *(const short8v*)(ap);
      short8v a1 = *(const short8v*)(ap + 32);
      f32x4 acc = z;
      acc = __builtin_amdgcn_mfma_f32_16x16x32_bf16(a0, B20, acc, 0, 0, 0);
      acc = __builtin_amdgcn_mfma_f32_16x16x32_bf16(a1, B21, acc, 0, 0, 0);
#pragma unroll
      for (int r = 0; r < 4; ++r){
        int el = mf * 16 + lg * 4 + r;
        int eid = eidx[tile + el];
        float rv = acc[r] + c2b + e[(size_t)eid * 64 + dloc];
        racc[mf][r] = rv;
        float s = rv, q2 = rv * rv;
        s  += __shfl_xor(s, 1);  s  += __shfl_xor(s, 2);  s  += __shfl_xor(s, 4);  s  += __shfl_xor(s, 8);
        q2 += __shfl_xor(q2, 1); q2 += __shfl_xor(q2, 2); q2 += __shfl_xor(q2, 4); q2 += __shfl_xor(q2, 8);
        if (li == 0){ reds[el][w] = s; redq[el][w] = q2; }
      }
    }
  }
  __syncthreads();

  // --- phase E: LN2c + scatter store by eid ---
  float g2v = g2c[dloc], b2v = b2c[dloc];
#pragma unroll
  for (int mf = 0; mf < 4; ++mf){
#pragma unroll
    for (int r = 0; r < 4; ++r){
      int el = mf * 16 + lg * 4 + r;
      int eid = eidx[tile + el];
      float S  = reds[el][0] + reds[el][1] + reds[el][2] + reds[el][3];
      float Qq = redq[el][0] + redq[el][1] + redq[el][2] + redq[el][3];
      float mu2 = S * (1.f/64.f);
      float var2 = Qq * (1.f/64.f) - mu2 * mu2;
      float rs2 = rsqrtf(fmaxf(var2, 0.f) + 1e-5f);
      out_conn[(size_t)eid * 64 + dloc] = (racc[mf][r] - mu2) * rs2 * g2v + b2v;
    }
  }
}

// ---------- K_agg: wave per node; cm/sexp sequential, V gathered ----------
__global__ __launch_bounds__(256) void k_agg(
    const int* __restrict__ start, const int* __restrict__ sid,
    const float* __restrict__ sexp, const bf16u* __restrict__ cm, const float* __restrict__ V,
    const float* __restrict__ x, float* __restrict__ hpre){
  int wid = (blockIdx.x * 256 + threadIdx.x) >> 6;
  int lane = threadIdx.x & 63;
  if (wid >= NN) return;
  int s0 = start[wid], s1 = start[wid + 1];
  int h = lane >> 4;
  float num = 0.f, den = 0.f;
  for (int i = s0; i < s1; ++i){
    float sx = sexp[(size_t)i * 4 + h];
    int sn = sid[i];
    float v  = V[(size_t)sn * 64 + lane];
    float cc = bf2f(cm[(size_t)i * 64 + lane]);
    num += sx * (v + cc);
    den += sx;
  }
  hpre[(size_t)wid * 64 + lane] = x[(size_t)wid * 64 + lane] + num / (den + 1e-16f);
}

// ---------- K5: node final — LN1h + FFN (MFMA) + LN2h ----------
__global__ __launch_bounds__(256) void k5_node(
    const float* __restrict__ hpre,
    const float* __restrict__ g1, const float* __restrict__ b1,
    const bf16u* __restrict__ BpF1, const float* __restrict__ ffn1_b,
    const bf16u* __restrict__ BpF2, const float* __restrict__ ffn2_b,
    const float* __restrict__ g2, const float* __restrict__ b2,
    float* __restrict__ out_h){
  __shared__ bf16u hlhi[64 * 72];
  __shared__ bf16u hllo[64 * 72];
  __shared__ bf16u g1o[64 * 136];
  __shared__ float reds[64][4];
  __shared__ float redq[64][4];
  int tile = blockIdx.x * 64;
  int t = threadIdx.x;
  {
    int el = t >> 2, q = t & 3;
    int row = tile + el;
    bool g = row < NN;
    float v[16];
    if (g){
      const float4* hp = (const float4*)(hpre + (size_t)row * 64 + q * 16);
#pragma unroll
      for (int c = 0; c < 4; ++c){
        float4 tv = hp[c];
        v[c*4+0]=tv.x; v[c*4+1]=tv.y; v[c*4+2]=tv.z; v[c*4+3]=tv.w;
      }
    } else {
#pragma unroll
      for (int i = 0; i < 16; ++i) v[i] = 0.f;
    }
    float s = 0.f, sq = 0.f;
#pragma unroll
    for (int i = 0; i < 16; ++i){ s += v[i]; sq += v[i]*v[i]; }
    s  += __shfl_xor(s, 1);  s  += __shfl_xor(s, 2);
    sq += __shfl_xor(sq, 1); sq += __shfl_xor(sq, 2);
    float mu = s * (1.f/64.f);
    float var = sq * (1.f/64.f) - mu * mu;
    float rs = rsqrtf(fmaxf(var, 0.f) + 1e-5f);
#pragma unroll
    for (int i = 0; i < 16; ++i){
      int d = q * 16 + i;
      float hv = (v[i] - mu) * rs * g1[d] + b1[d];
      bf16u hb = f2bf(hv);
      hlhi[el * 72 + d] = hb;
      hllo[el * 72 + d] = f2bf(hv - bf2f(hb));
    }
  }
  __syncthreads();
  int w = t >> 6, l = t & 63;
  int lg = l >> 4, li = l & 15;
  const short8v* bpf1 = (const short8v*)BpF1;
  short8v B1f[2][2];
#pragma unroll
  for (int f = 0; f < 2; ++f)
#pragma unroll
    for (int ks = 0; ks < 2; ++ks)
      B1f[f][ks] = bpf1[(ks * 8 + f * 4 + w) * 64 + l];
  f32x4 z = {0.f, 0.f, 0.f, 0.f};
  f32x4 acc1[2][4];
#pragma unroll
  for (int f = 0; f < 2; ++f)
#pragma unroll
    for (int mf = 0; mf < 4; ++mf) acc1[f][mf] = z;
#pragma unroll
  for (int mf = 0; mf < 4; ++mf){
#pragma unroll
    for (int ks = 0; ks < 2; ++ks){
      const bf16u* ah = &hlhi[(mf * 16 + li) * 72 + ks * 32 + lg * 8];
      const bf16u* al = &hllo[(mf * 16 + li) * 72 + ks * 32 + lg * 8];
      short8v Ahi = *(const short8v*)ah;
      short8v Alo = *(const short8v*)al;
#pragma unroll
      for (int f = 0; f < 2; ++f){
        acc1[f][mf] = __builtin_amdgcn_mfma_f32_16x16x32_bf16(Ahi, B1f[f][ks], acc1[f][mf], 0, 0, 0);
        acc1[f][mf] = __builtin_amdgcn_mfma_f32_16x16x32_bf16(Alo, B1f[f][ks], acc1[f][mf], 0, 0, 0);
      }
    }
  }
  float fb[2] = {ffn1_b[w*16+li], ffn1_b[64+w*16+li]};
#pragma unroll
  for (int f = 0; f < 2; ++f)
#pragma unroll
    for (int mf = 0; mf < 4; ++mf)
#pragma unroll
      for (int r = 0; r < 4; ++r){
        int rowl = mf * 16 + lg * 4 + r;
        int col = f * 64 + w * 16 + li;
        g1o[rowl * 136 + col] = f2bf(fmaxf(acc1[f][mf][r] + fb[f], 0.f));
      }
  __syncthreads();
  const short8v* bpf2 = (const short8v*)BpF2;
  short8v B2f[4];
#pragma unroll
  for (int ks = 0; ks < 4; ++ks) B2f[ks] = bpf2[(ks * 4 + w) * 64 + l];
  int o = w * 16 + li;
  float f2b_ = ffn2_b[o];
  float racc[4][4];
#pragma unroll
  for (int mf = 0; mf < 4; ++mf){
    f32x4 acc = z;
#pragma unroll
    for (int ks = 0; ks < 4; ++ks){
      short8v A2 = *(const short8v*)&g1o[(mf * 16 + li) * 136 + ks * 32 + lg * 8];
      acc = __builtin_amdgcn_mfma_f32_16x16x32_bf16(A2, B2f[ks], acc, 0, 0, 0);
    }
#pragma unroll
    for (int r = 0; r < 4; ++r){
      int rowl = mf * 16 + lg * 4 + r;
      int row = tile + rowl;
      float hres = (row < NN) ? hpre[(size_t)row * 64 + o] : 0.f;
      float rv = acc[r] + f2b_ + hres;
      racc[mf][r] = rv;
      float s = rv, q2 = rv * rv;
      s  += __shfl_xor(s, 1);  s  += __shfl_xor(s, 2);  s  += __shfl_xor(s, 4);  s  += __shfl_xor(s, 8);
      q2 += __shfl_xor(q2, 1); q2 += __shfl_xor(q2, 2); q2 += __shfl_xor(q2, 4); q2 += __shfl_xor(q2, 8);
      if (li == 0){ reds[rowl][w] = s; redq[rowl][w] = q2; }
    }
  }
  __syncthreads();
  float g2v = g2[o], b2v = b2[o];
#pragma unroll
  for (int mf = 0; mf < 4; ++mf){
#pragma unroll
    for (int r = 0; r < 4; ++r){
      int rowl = mf * 16 + lg * 4 + r;
      int row = tile + rowl;
      if (row < NN){
        float S  = reds[rowl][0] + reds[rowl][1] + reds[rowl][2] + reds[rowl][3];
        float Qq = redq[rowl][0] + redq[rowl][1] + redq[rowl][2] + redq[rowl][3];
        float mu2 = S * (1.f/64.f);
        float var2 = Qq * (1.f/64.f) - mu2 * mu2;
        float rs2 = rsqrtf(fmaxf(var2, 0.f) + 1e-5f);
        out_h[(size_t)row * 64 + o] = (racc[mf][r] - mu2) * rs2 * g2v + b2v;
      }
    }
  }
}

extern "C" void kernel_launch(void* const* d_in, const int* in_sizes, int n_in,
                              void* d_out, int out_size, void* d_ws, size_t ws_size,
                              hipStream_t stream){
  const float* x       = (const float*)d_in[0];
  const float* e       = (const float*)d_in[1];
  const int*   dst     = (const int*)d_in[2];
  const int*   src     = (const int*)d_in[3];
  const float* qkv_w   = (const float*)d_in[4];
  const float* qkv_b   = (const float*)d_in[5];
  const float* E_w     = (const float*)d_in[6];
  const float* E_b     = (const float*)d_in[7];
  const float* Aw      = (const float*)d_in[8];
  const float* conn1_w = (const float*)d_in[9];
  const float* conn1_b = (const float*)d_in[10];
  const float* conn2_w = (const float*)d_in[11];
  const float* conn2_b = (const float*)d_in[12];
  const float* ffn1_w  = (const float*)d_in[13];
  const float* ffn1_b  = (const float*)d_in[14];
  const float* ffn2_w  = (const float*)d_in[15];
  const float* ffn2_b  = (const float*)d_in[16];
  const float* ln1h_g  = (const float*)d_in[17];
  const float* ln1h_b  = (const float*)d_in[18];
  const float* ln2h_g  = (const float*)d_in[19];
  const float* ln2h_b  = (const float*)d_in[20];
  const float* ln1c_g  = (const float*)d_in[21];
  const float* ln1c_b  = (const float*)d_in[22];
  const float* ln2c_g  = (const float*)d_in[23];
  const float* ln2c_b  = (const float*)d_in[24];

  char* ws = (char*)d_ws;
  size_t off = 0;
  auto alloc = [&](size_t bytes) -> void* {
    void* p = ws + off;
    off += (bytes + 255) & ~(size_t)255;
    return p;
  };
  float* Q     = (float*)alloc((size_t)NN * 64 * 4);
  float* Kq    = (float*)alloc((size_t)NN * 64 * 4);
  float* V     = (float*)alloc((size_t)NN * 64 * 4);
  bf16u* cmb   = (bf16u*)alloc((size_t)NE * 64 * 2);
  float* sexp  = (float*)alloc((size_t)NE * 4 * 4);
  float* hpre  = (float*)alloc((size_t)NN * 64 * 4);
  bf16u* BpE   = (bf16u*)alloc(8192 * 2);
  bf16u* Bp1   = (bf16u*)alloc(4096 * 2);
  bf16u* Bp2   = (bf16u*)alloc(4096 * 2);
  bf16u* BpQ   = (bf16u*)alloc(12288 * 2);
  bf16u* BpF1  = (bf16u*)alloc(8192 * 2);
  bf16u* BpF2  = (bf16u*)alloc(8192 * 2);
  int*   cnt   = (int*)alloc((size_t)NN * 4);
  int*   startp= (int*)alloc(((size_t)NN + 1) * 4);
  int*   cursor= (int*)alloc((size_t)NN * 4);
  int*   eidx  = (int*)alloc((size_t)NE * 4);
  int*   nid   = (int*)alloc((size_t)NE * 4);
  int*   sid   = (int*)alloc((size_t)NE * 4);

  float* out_h    = (float*)d_out;
  float* out_conn = out_h + (size_t)NN * 64;

  hipMemsetAsync(cnt, 0, (size_t)NN * 4, stream);

  k0_pack<<<48, 256, 0, stream>>>(E_w, conn1_w, conn2_w, qkv_w, ffn1_w, ffn2_w,
                                  BpE, Bp1, Bp2, BpQ, BpF1, BpF2);
  k_hist<<<NE / 256, 256, 0, stream>>>(dst, cnt);
  k_scan<<<1, SCAN_T, 0, stream>>>(cnt, startp, cursor);
  k_scatter<<<NE / 256, 256, 0, stream>>>(dst, src, cursor, eidx, nid, sid);
  k1_qkv<<<(NN + 63) / 64, 256, 0, stream>>>(x, BpQ, qkv_b, Q, Kq, V);
  k2_edge<<<NE / 64, 256, 0, stream>>>(e, eidx, nid, sid, BpE, E_b, Aw, Bp1, conn1_b,
                                       Q, Kq, ln1c_g, ln1c_b, Bp2, conn2_b,
                                       ln2c_g, ln2c_b, cmb, sexp, out_conn);
  k_agg<<<(NN * 64 + 255) / 256, 256, 0, stream>>>(startp, sid, sexp, cmb, V, x, hpre);
  k5_node<<<(NN + 63) / 64, 256, 0, stream>>>(hpre, ln1h_g, ln1h_b, BpF1, ffn1_b,
                                              BpF2, ffn2_b, ln2h_g, ln2h_b, out_h);
}

// Round 9
// 627.715 us; speedup vs baseline: 2.4890x; 1.0162x over previous
//
#include <hip/hip_runtime.h>
#include <cstdint>

#define NN 50000
#define NE 512000

typedef unsigned short bf16u;
typedef __attribute__((ext_vector_type(8))) short short8v;
typedef __attribute__((ext_vector_type(4))) float f32x4;

__device__ __forceinline__ bf16u f2bf(float f){
  union { float f; unsigned int u; } v; v.f = f;
  unsigned int r = v.u + 0x7FFFu + ((v.u >> 16) & 1u);
  return (bf16u)(r >> 16);
}
__device__ __forceinline__ float bf2f(bf16u s){
  union { unsigned int u; float f; } v; v.u = ((unsigned int)s) << 16;
  return v.f;
}

// ---------- K0: weight packing into MFMA B-fragments ----------
// B-frag layout (mfma_f32_16x16x32_bf16): elem [((ks*NF+nf)*64+l)*8+j] =
//   W[n][k],  n = nf*16 + (l&15),  k = ks*32 + ((l>>4)<<3) + j
__global__ void k0_pack(const float* __restrict__ E_w, const float* __restrict__ conn1_w,
                        const float* __restrict__ conn2_w, const float* __restrict__ qkv_w,
                        const float* __restrict__ ffn1_w, const float* __restrict__ ffn2_w,
                        bf16u* __restrict__ BpE, bf16u* __restrict__ Bp1,
                        bf16u* __restrict__ Bp2, bf16u* __restrict__ BpQ,
                        bf16u* __restrict__ BpF1, bf16u* __restrict__ BpF2){
  int i = blockIdx.x * 256 + threadIdx.x;   // 0..12287
  int j = i & 7, l = (i >> 3) & 63;
  int nl = l & 15, kl = (l >> 4) << 3;
  if (i < 8192){   // E_w: (128,64), NF=8, KS=2
    int rest = i >> 9, nf = rest & 7, ks = rest >> 3;
    int n = nf * 16 + nl, k = ks * 32 + kl + j;
    BpE[i] = f2bf(E_w[n * 64 + k]);
  }
  if (i < 4096){   // conn1_w/conn2_w: (64,64), NF=4, KS=2
    int rest = i >> 9, nf = rest & 3, ks = rest >> 2;
    int n = nf * 16 + nl, k = ks * 32 + kl + j;
    Bp1[i] = f2bf(conn1_w[n * 64 + k]);
    Bp2[i] = f2bf(conn2_w[n * 64 + k]);
  }
  if (i < 12288){  // qkv_w: (192,64), NF=12, KS=2
    int rest = i >> 9, nf = rest % 12, ks = rest / 12;
    int n = nf * 16 + nl, k = ks * 32 + kl + j;
    BpQ[i] = f2bf(qkv_w[n * 64 + k]);
  }
  if (i < 8192){   // ffn1_w: (128,64), NF=8, KS=2
    int rest = i >> 9, nf = rest & 7, ks = rest >> 3;
    int n = nf * 16 + nl, k = ks * 32 + kl + j;
    BpF1[i] = f2bf(ffn1_w[n * 64 + k]);
  }
  if (i < 8192){   // ffn2_w: (64,128), NF=4, KS=4
    int rest = i >> 9, nf = rest & 3, ks = rest >> 2;
    int n = nf * 16 + nl, k = ks * 32 + kl + j;
    BpF2[i] = f2bf(ffn2_w[n * 128 + k]);
  }
}

// ---------- CSR build ----------
__global__ void k_hist(const int* __restrict__ dst, int* __restrict__ cnt){
  int e = blockIdx.x * 256 + threadIdx.x;
  if (e < NE) atomicAdd(&cnt[dst[e]], 1);
}

#define SCAN_T 1024
#define PER_T 49
__global__ __launch_bounds__(SCAN_T) void k_scan(const int* __restrict__ cnt,
                                                 int* __restrict__ start, int* __restrict__ cursor){
  __shared__ int ls[SCAN_T];
  int t = threadIdx.x;
  int base = t * PER_T;
  int s = 0;
  for (int i = 0; i < PER_T; ++i){ int n = base + i; if (n < NN) s += cnt[n]; }
  ls[t] = s; __syncthreads();
  for (int off = 1; off < SCAN_T; off <<= 1){
    int v = ls[t];
    int add = (t >= off) ? ls[t - off] : 0;
    __syncthreads();
    ls[t] = v + add;
    __syncthreads();
  }
  int run = (t > 0) ? ls[t - 1] : 0;
  for (int i = 0; i < PER_T; ++i){
    int n = base + i;
    if (n < NN){ start[n] = run; cursor[n] = run; run += cnt[n]; }
  }
  if (t == SCAN_T - 1) start[NN] = run;
}

__global__ void k_scatter(const int* __restrict__ dst, const int* __restrict__ src,
                          int* __restrict__ cursor, int* __restrict__ eidx,
                          int* __restrict__ nid, int* __restrict__ sid){
  int e = blockIdx.x * 256 + threadIdx.x;
  if (e < NE){
    int dn = dst[e];
    int p = atomicAdd(&cursor[dn], 1);
    eidx[p] = e;
    nid[p] = dn;
    sid[p] = src[e];
  }
}

// ---------- K1: node QKV — MFMA, split-bf16 A ----------
__global__ __launch_bounds__(256) void k1_qkv(const float* __restrict__ x,
    const bf16u* __restrict__ BpQ, const float* __restrict__ qkv_b,
    float* __restrict__ Q, float* __restrict__ K, float* __restrict__ V){
  int tile = blockIdx.x * 64;
  int w = threadIdx.x >> 6, l = threadIdx.x & 63;
  int lg = l >> 4, li = l & 15;
  const short8v* bpq = (const short8v*)BpQ;
  short8v Bq[3][2];
#pragma unroll
  for (int p = 0; p < 3; ++p)
#pragma unroll
    for (int ks = 0; ks < 2; ++ks)
      Bq[p][ks] = bpq[(ks * 12 + p * 4 + w) * 64 + l];
  f32x4 z = {0.f, 0.f, 0.f, 0.f};
  f32x4 acc[3][4];
#pragma unroll
  for (int p = 0; p < 3; ++p)
#pragma unroll
    for (int mf = 0; mf < 4; ++mf) acc[p][mf] = z;
#pragma unroll
  for (int mf = 0; mf < 4; ++mf){
    int row = tile + mf * 16 + li;
    bool g = row < NN;
    const float* xp = x + (size_t)row * 64 + lg * 8;
#pragma unroll
    for (int ks = 0; ks < 2; ++ks){
      float v[8];
      if (g){
        float4 t0 = *(const float4*)(xp + ks * 32);
        float4 t1 = *(const float4*)(xp + ks * 32 + 4);
        v[0]=t0.x; v[1]=t0.y; v[2]=t0.z; v[3]=t0.w;
        v[4]=t1.x; v[5]=t1.y; v[6]=t1.z; v[7]=t1.w;
      } else {
#pragma unroll
        for (int j = 0; j < 8; ++j) v[j] = 0.f;
      }
      short8v hi, lo;
#pragma unroll
      for (int j = 0; j < 8; ++j){
        bf16u h = f2bf(v[j]);
        hi[j] = (short)h;
        lo[j] = (short)f2bf(v[j] - bf2f(h));
      }
#pragma unroll
      for (int p = 0; p < 3; ++p){
        acc[p][mf] = __builtin_amdgcn_mfma_f32_16x16x32_bf16(hi, Bq[p][ks], acc[p][mf], 0, 0, 0);
        acc[p][mf] = __builtin_amdgcn_mfma_f32_16x16x32_bf16(lo, Bq[p][ks], acc[p][mf], 0, 0, 0);
      }
    }
  }
  float bias[3] = {qkv_b[w*16+li], qkv_b[64+w*16+li], qkv_b[128+w*16+li]};
  float* outs[3] = {Q, K, V};
#pragma unroll
  for (int p = 0; p < 3; ++p)
#pragma unroll
    for (int mf = 0; mf < 4; ++mf)
#pragma unroll
      for (int r = 0; r < 4; ++r){
        int row = tile + mf * 16 + lg * 4 + r;
        if (row < NN) outs[p][(size_t)row * 64 + w * 16 + li] = acc[p][mf][r] + bias[p];
      }
}

// ---------- K2: fused edge kernel, CSR-ordered, 6 waves/SIMD budget ----------
__global__ __launch_bounds__(256, 6) void k2_edge(
    const float* __restrict__ e, const int* __restrict__ eidx,
    const int* __restrict__ nid, const int* __restrict__ sid,
    const bf16u* __restrict__ BpE, const float* __restrict__ E_b,
    const float* __restrict__ Aw, const bf16u* __restrict__ Bp1, const float* __restrict__ conn1_b,
    const float* __restrict__ Q, const float* __restrict__ K,
    const float* __restrict__ g1c, const float* __restrict__ b1c,
    const bf16u* __restrict__ Bp2, const float* __restrict__ conn2_b,
    const float* __restrict__ g2c, const float* __restrict__ b2c,
    bf16u* __restrict__ cm, float* __restrict__ sexp, float* __restrict__ out_conn){
  __shared__ bf16u cpre[64 * 72];
  __shared__ bf16u cmid[64 * 72];
  __shared__ float reds[64][4];
  __shared__ float redq[64][4];
  int tile = blockIdx.x * 64;
  int w = threadIdx.x >> 6, l = threadIdx.x & 63;
  int lg = l >> 4, li = l & 15;
  int dloc = w * 16 + li;

  float eb0 = E_b[dloc], eb1 = E_b[64 + dloc];
  float awv = Aw[li * 4 + w];
  f32x4 z = {0.f, 0.f, 0.f, 0.f};

  // --- phase A: per-mf Eh MFMA + pointwise ---
  {
    const short8v* bpe = (const short8v*)BpE;
    short8v BW0 = bpe[(0*8 + w)     * 64 + l];
    short8v BW1 = bpe[(1*8 + w)     * 64 + l];
    short8v BB0 = bpe[(0*8 + 4 + w) * 64 + l];
    short8v BB1 = bpe[(1*8 + 4 + w) * 64 + l];
#pragma unroll
    for (int mf = 0; mf < 4; ++mf){
      int eidA = eidx[tile + mf * 16 + li];
      const float* ep = e + (size_t)eidA * 64 + lg * 8;
      f32x4 accW = z, accB = z;
#pragma unroll
      for (int ks = 0; ks < 2; ++ks){
        float4 a0 = *(const float4*)(ep + ks * 32);
        float4 a1 = *(const float4*)(ep + ks * 32 + 4);
        short8v af;
        af[0]=(short)f2bf(a0.x); af[1]=(short)f2bf(a0.y); af[2]=(short)f2bf(a0.z); af[3]=(short)f2bf(a0.w);
        af[4]=(short)f2bf(a1.x); af[5]=(short)f2bf(a1.y); af[6]=(short)f2bf(a1.z); af[7]=(short)f2bf(a1.w);
        accW = __builtin_amdgcn_mfma_f32_16x16x32_bf16(af, ks ? BW1 : BW0, accW, 0, 0, 0);
        accB = __builtin_amdgcn_mfma_f32_16x16x32_bf16(af, ks ? BB1 : BB0, accB, 0, 0, 0);
      }
#pragma unroll
      for (int r = 0; r < 4; ++r){
        int el = mf * 16 + lg * 4 + r;
        int pos = tile + el;
        int dn = nid[pos], sn = sid[pos];
        float qv = Q[(size_t)dn * 64 + dloc];
        float kv = K[(size_t)sn * 64 + dloc];
        float ew  = accW[r] + eb0;
        float ebv = accB[r] + eb1;
        float c1 = (qv + kv) * ew;
        float c2 = copysignf(sqrtf(fabsf(c1)), c1);
        float cpv = fmaxf(c2 + ebv, 0.f);
        float s = cpv * awv;
        s += __shfl_xor(s, 1); s += __shfl_xor(s, 2);
        s += __shfl_xor(s, 4); s += __shfl_xor(s, 8);
        if (li == 0){
          float sc = fminf(fmaxf(s, -5.f), 5.f);
          sexp[(size_t)pos * 4 + w] = __expf(sc);
        }
        cpre[el * 72 + dloc] = f2bf(cpv);
      }
    }
  }
  __syncthreads();

  // --- phase B: conn1 MFMA; store cm global + cmid LDS; LN1c stats (f32) ---
  float c1b = conn1_b[dloc];
  {
    const short8v* bp1 = (const short8v*)Bp1;
    short8v B10 = bp1[(0*4 + w) * 64 + l];
    short8v B11 = bp1[(1*4 + w) * 64 + l];
#pragma unroll
    for (int mf = 0; mf < 4; ++mf){
      const bf16u* ap = &cpre[(mf * 16 + li) * 72 + lg * 8];
      short8v a0 = *(const short8v*)(ap);
      short8v a1 = *(const short8v*)(ap + 32);
      f32x4 acc = z;
      acc = __builtin_amdgcn_mfma_f32_16x16x32_bf16(a0, B10, acc, 0, 0, 0);
      acc = __builtin_amdgcn_mfma_f32_16x16x32_bf16(a1, B11, acc, 0, 0, 0);
#pragma unroll
      for (int r = 0; r < 4; ++r){
        int el = mf * 16 + lg * 4 + r;
        float v = acc[r] + c1b;
        bf16u vb = f2bf(v);
        cm[(size_t)(tile + el) * 64 + dloc] = vb;
        cmid[el * 72 + dloc] = vb;
        float s = v, q2 = v * v;
        s  += __shfl_xor(s, 1);  s  += __shfl_xor(s, 2);  s  += __shfl_xor(s, 4);  s  += __shfl_xor(s, 8);
        q2 += __shfl_xor(q2, 1); q2 += __shfl_xor(q2, 2); q2 += __shfl_xor(q2, 4); q2 += __shfl_xor(q2, 8);
        if (li == 0){ reds[el][w] = s; redq[el][w] = q2; }
      }
    }
  }
  __syncthreads();

  // --- phase C: LN1c normalize + relu -> cpre (overwrite) ---
  float g1v = g1c[dloc], b1v = b1c[dloc];
#pragma unroll
  for (int mf = 0; mf < 4; ++mf){
#pragma unroll
    for (int r = 0; r < 4; ++r){
      int el = mf * 16 + lg * 4 + r;
      float S  = reds[el][0] + reds[el][1] + reds[el][2] + reds[el][3];
      float Qq = redq[el][0] + redq[el][1] + redq[el][2] + redq[el][3];
      float mu = S * (1.f/64.f);
      float var = Qq * (1.f/64.f) - mu * mu;
      float rs = rsqrtf(fmaxf(var, 0.f) + 1e-5f);
      float cv = bf2f(cmid[el * 72 + dloc]);
      float cn = fmaxf((cv - mu) * rs * g1v + b1v, 0.f);
      cpre[el * 72 + dloc] = f2bf(cn);
    }
  }
  __syncthreads();

  // --- phase D: conn2 MFMA + residual + LN2c stats (racc in regs) ---
  float c2b = conn2_b[dloc];
  float racc[4][4];
  {
    const short8v* bp2 = (const short8v*)Bp2;
    short8v B20 = bp2[(0*4 + w) * 64 + l];
    short8v B21 = bp2[(1*4 + w) * 64 + l];
#pragma unroll
    for (int mf = 0; mf < 4; ++mf){
      const bf16u* ap = &cpre[(mf * 16 + li) * 72 + lg * 8];
      short8v a0 = *(const short8v*)(ap);
      short8v a1 = *(const short8v*)(ap + 32);
      f32x4 acc = z;
      acc = __builtin_amdgcn_mfma_f32_16x16x32_bf16(a0, B20, acc, 0, 0, 0);
      acc = __builtin_amdgcn_mfma_f32_16x16x32_bf16(a1, B21, acc, 0, 0, 0);
#pragma unroll
      for (int r = 0; r < 4; ++r){
        int el = mf * 16 + lg * 4 + r;
        int eid = eidx[tile + el];
        float rv = acc[r] + c2b + e[(size_t)eid * 64 + dloc];
        racc[mf][r] = rv;
        float s = rv, q2 = rv * rv;
        s  += __shfl_xor(s, 1);  s  += __shfl_xor(s, 2);  s  += __shfl_xor(s, 4);  s  += __shfl_xor(s, 8);
        q2 += __shfl_xor(q2, 1); q2 += __shfl_xor(q2, 2); q2 += __shfl_xor(q2, 4); q2 += __shfl_xor(q2, 8);
        if (li == 0){ reds[el][w] = s; redq[el][w] = q2; }
      }
    }
  }
  __syncthreads();

  // --- phase E: LN2c + scatter store by eid ---
  float g2v = g2c[dloc], b2v = b2c[dloc];
#pragma unroll
  for (int mf = 0; mf < 4; ++mf){
#pragma unroll
    for (int r = 0; r < 4; ++r){
      int el = mf * 16 + lg * 4 + r;
      int eid = eidx[tile + el];
      float S  = reds[el][0] + reds[el][1] + reds[el][2] + reds[el][3];
      float Qq = redq[el][0] + redq[el][1] + redq[el][2] + redq[el][3];
      float mu2 = S * (1.f/64.f);
      float var2 = Qq * (1.f/64.f) - mu2 * mu2;
      float rs2 = rsqrtf(fmaxf(var2, 0.f) + 1e-5f);
      out_conn[(size_t)eid * 64 + dloc] = (racc[mf][r] - mu2) * rs2 * g2v + b2v;
    }
  }
}

// ---------- K_agg: wave per node; cm/sexp sequential, V gathered ----------
__global__ __launch_bounds__(256) void k_agg(
    const int* __restrict__ start, const int* __restrict__ sid,
    const float* __restrict__ sexp, const bf16u* __restrict__ cm, const float* __restrict__ V,
    const float* __restrict__ x, float* __restrict__ hpre){
  int wid = (blockIdx.x * 256 + threadIdx.x) >> 6;
  int lane = threadIdx.x & 63;
  if (wid >= NN) return;
  int s0 = start[wid], s1 = start[wid + 1];
  int h = lane >> 4;
  float num = 0.f, den = 0.f;
  for (int i = s0; i < s1; ++i){
    float sx = sexp[(size_t)i * 4 + h];
    int sn = sid[i];
    float v  = V[(size_t)sn * 64 + lane];
    float cc = bf2f(cm[(size_t)i * 64 + lane]);
    num += sx * (v + cc);
    den += sx;
  }
  hpre[(size_t)wid * 64 + lane] = x[(size_t)wid * 64 + lane] + num / (den + 1e-16f);
}

// ---------- K5: node final — LN1h + FFN (MFMA) + LN2h ----------
__global__ __launch_bounds__(256) void k5_node(
    const float* __restrict__ hpre,
    const float* __restrict__ g1, const float* __restrict__ b1,
    const bf16u* __restrict__ BpF1, const float* __restrict__ ffn1_b,
    const bf16u* __restrict__ BpF2, const float* __restrict__ ffn2_b,
    const float* __restrict__ g2, const float* __restrict__ b2,
    float* __restrict__ out_h){
  __shared__ bf16u hlhi[64 * 72];
  __shared__ bf16u hllo[64 * 72];
  __shared__ bf16u g1o[64 * 136];
  __shared__ float reds[64][4];
  __shared__ float redq[64][4];
  int tile = blockIdx.x * 64;
  int t = threadIdx.x;
  {
    int el = t >> 2, q = t & 3;
    int row = tile + el;
    bool g = row < NN;
    float v[16];
    if (g){
      const float4* hp = (const float4*)(hpre + (size_t)row * 64 + q * 16);
#pragma unroll
      for (int c = 0; c < 4; ++c){
        float4 tv = hp[c];
        v[c*4+0]=tv.x; v[c*4+1]=tv.y; v[c*4+2]=tv.z; v[c*4+3]=tv.w;
      }
    } else {
#pragma unroll
      for (int i = 0; i < 16; ++i) v[i] = 0.f;
    }
    float s = 0.f, sq = 0.f;
#pragma unroll
    for (int i = 0; i < 16; ++i){ s += v[i]; sq += v[i]*v[i]; }
    s  += __shfl_xor(s, 1);  s  += __shfl_xor(s, 2);
    sq += __shfl_xor(sq, 1); sq += __shfl_xor(sq, 2);
    float mu = s * (1.f/64.f);
    float var = sq * (1.f/64.f) - mu * mu;
    float rs = rsqrtf(fmaxf(var, 0.f) + 1e-5f);
#pragma unroll
    for (int i = 0; i < 16; ++i){
      int d = q * 16 + i;
      float hv = (v[i] - mu) * rs * g1[d] + b1[d];
      bf16u hb = f2bf(hv);
      hlhi[el * 72 + d] = hb;
      hllo[el * 72 + d] = f2bf(hv - bf2f(hb));
    }
  }
  __syncthreads();
  int w = t >> 6, l = t & 63;
  int lg = l >> 4, li = l & 15;
  const short8v* bpf1 = (const short8v*)BpF1;
  short8v B1f[2][2];
#pragma unroll
  for (int f = 0; f < 2; ++f)
#pragma unroll
    for (int ks = 0; ks < 2; ++ks)
      B1f[f][ks] = bpf1[(ks * 8 + f * 4 + w) * 64 + l];
  f32x4 z = {0.f, 0.f, 0.f, 0.f};
  f32x4 acc1[2][4];
#pragma unroll
  for (int f = 0; f < 2; ++f)
#pragma unroll
    for (int mf = 0; mf < 4; ++mf) acc1[f][mf] = z;
#pragma unroll
  for (int mf = 0; mf < 4; ++mf){
#pragma unroll
    for (int ks = 0; ks < 2; ++ks){
      const bf16u* ah = &hlhi[(mf * 16 + li) * 72 + ks * 32 + lg * 8];
      const bf16u* al = &hllo[(mf * 16 + li) * 72 + ks * 32 + lg * 8];
      short8v Ahi = *(const short8v*)ah;
      short8v Alo = *(const short8v*)al;
#pragma unroll
      for (int f = 0; f < 2; ++f){
        acc1[f][mf] = __builtin_amdgcn_mfma_f32_16x16x32_bf16(Ahi, B1f[f][ks], acc1[f][mf], 0, 0, 0);
        acc1[f][mf] = __builtin_amdgcn_mfma_f32_16x16x32_bf16(Alo, B1f[f][ks], acc1[f][mf], 0, 0, 0);
      }
    }
  }
  float fb[2] = {ffn1_b[w*16+li], ffn1_b[64+w*16+li]};
#pragma unroll
  for (int f = 0; f < 2; ++f)
#pragma unroll
    for (int mf = 0; mf < 4; ++mf)
#pragma unroll
      for (int r = 0; r < 4; ++r){
        int rowl = mf * 16 + lg * 4 + r;
        int col = f * 64 + w * 16 + li;
        g1o[rowl * 136 + col] = f2bf(fmaxf(acc1[f][mf][r] + fb[f], 0.f));
      }
  __syncthreads();
  const short8v* bpf2 = (const short8v*)BpF2;
  short8v B2f[4];
#pragma unroll
  for (int ks = 0; ks < 4; ++ks) B2f[ks] = bpf2[(ks * 4 + w) * 64 + l];
  int o = w * 16 + li;
  float f2b_ = ffn2_b[o];
  float racc[4][4];
#pragma unroll
  for (int mf = 0; mf < 4; ++mf){
    f32x4 acc = z;
#pragma unroll
    for (int ks = 0; ks < 4; ++ks){
      short8v A2 = *(const short8v*)&g1o[(mf * 16 + li) * 136 + ks * 32 + lg * 8];
      acc = __builtin_amdgcn_mfma_f32_16x16x32_bf16(A2, B2f[ks], acc, 0, 0, 0);
    }
#pragma unroll
    for (int r = 0; r < 4; ++r){
      int rowl = mf * 16 + lg * 4 + r;
      int row = tile + rowl;
      float hres = (row < NN) ? hpre[(size_t)row * 64 + o] : 0.f;
      float rv = acc[r] + f2b_ + hres;
      racc[mf][r] = rv;
      float s = rv, q2 = rv * rv;
      s  += __shfl_xor(s, 1);  s  += __shfl_xor(s, 2);  s  += __shfl_xor(s, 4);  s  += __shfl_xor(s, 8);
      q2 += __shfl_xor(q2, 1); q2 += __shfl_xor(q2, 2); q2 += __shfl_xor(q2, 4); q2 += __shfl_xor(q2, 8);
      if (li == 0){ reds[rowl][w] = s; redq[rowl][w] = q2; }
    }
  }
  __syncthreads();
  float g2v = g2[o], b2v = b2[o];
#pragma unroll
  for (int mf = 0; mf < 4; ++mf){
#pragma unroll
    for (int r = 0; r < 4; ++r){
      int rowl = mf * 16 + lg * 4 + r;
      int row = tile + rowl;
      if (row < NN){
        float S  = reds[rowl][0] + reds[rowl][1] + reds[rowl][2] + reds[rowl][3];
        float Qq = redq[rowl][0] + redq[rowl][1] + redq[rowl][2] + redq[rowl][3];
        float mu2 = S * (1.f/64.f);
        float var2 = Qq * (1.f/64.f) - mu2 * mu2;
        float rs2 = rsqrtf(fmaxf(var2, 0.f) + 1e-5f);
        out_h[(size_t)row * 64 + o] = (racc[mf][r] - mu2) * rs2 * g2v + b2v;
      }
    }
  }
}

extern "C" void kernel_launch(void* const* d_in, const int* in_sizes, int n_in,
                              void* d_out, int out_size, void* d_ws, size_t ws_size,
                              hipStream_t stream){
  const float* x       = (const float*)d_in[0];
  const float* e       = (const float*)d_in[1];
  const int*   dst     = (const int*)d_in[2];
  const int*   src     = (const int*)d_in[3];
  const float* qkv_w   = (const float*)d_in[4];
  const float* qkv_b   = (const float*)d_in[5];
  const float* E_w     = (const float*)d_in[6];
  const float* E_b     = (const float*)d_in[7];
  const float* Aw      = (const float*)d_in[8];
  const float* conn1_w = (const float*)d_in[9];
  const float* conn1_b = (const float*)d_in[10];
  const float* conn2_w = (const float*)d_in[11];
  const float* conn2_b = (const float*)d_in[12];
  const float* ffn1_w  = (const float*)d_in[13];
  const float* ffn1_b  = (const float*)d_in[14];
  const float* ffn2_w  = (const float*)d_in[15];
  const float* ffn2_b  = (const float*)d_in[16];
  const float* ln1h_g  = (const float*)d_in[17];
  const float* ln1h_b  = (const float*)d_in[18];
  const float* ln2h_g  = (const float*)d_in[19];
  const float* ln2h_b  = (const float*)d_in[20];
  const float* ln1c_g  = (const float*)d_in[21];
  const float* ln1c_b  = (const float*)d_in[22];
  const float* ln2c_g  = (const float*)d_in[23];
  const float* ln2c_b  = (const float*)d_in[24];

  char* ws = (char*)d_ws;
  size_t off = 0;
  auto alloc = [&](size_t bytes) -> void* {
    void* p = ws + off;
    off += (bytes + 255) & ~(size_t)255;
    return p;
  };
  float* Q     = (float*)alloc((size_t)NN * 64 * 4);
  float* Kq    = (float*)alloc((size_t)NN * 64 * 4);
  float* V     = (float*)alloc((size_t)NN * 64 * 4);
  bf16u* cmb   = (bf16u*)alloc((size_t)NE * 64 * 2);
  float* sexp  = (float*)alloc((size_t)NE * 4 * 4);
  float* hpre  = (float*)alloc((size_t)NN * 64 * 4);
  bf16u* BpE   = (bf16u*)alloc(8192 * 2);
  bf16u* Bp1   = (bf16u*)alloc(4096 * 2);
  bf16u* Bp2   = (bf16u*)alloc(4096 * 2);
  bf16u* BpQ   = (bf16u*)alloc(12288 * 2);
  bf16u* BpF1  = (bf16u*)alloc(8192 * 2);
  bf16u* BpF2  = (bf16u*)alloc(8192 * 2);
  int*   cnt   = (int*)alloc((size_t)NN * 4);
  int*   startp= (int*)alloc(((size_t)NN + 1) * 4);
  int*   cursor= (int*)alloc((size_t)NN * 4);
  int*   eidx  = (int*)alloc((size_t)NE * 4);
  int*   nid   = (int*)alloc((size_t)NE * 4);
  int*   sid   = (int*)alloc((size_t)NE * 4);

  float* out_h    = (float*)d_out;
  float* out_conn = out_h + (size_t)NN * 64;

  hipMemsetAsync(cnt, 0, (size_t)NN * 4, stream);

  k0_pack<<<48, 256, 0, stream>>>(E_w, conn1_w, conn2_w, qkv_w, ffn1_w, ffn2_w,
                                  BpE, Bp1, Bp2, BpQ, BpF1, BpF2);
  k_hist<<<NE / 256, 256, 0, stream>>>(dst, cnt);
  k_scan<<<1, SCAN_T, 0, stream>>>(cnt, startp, cursor);
  k_scatter<<<NE / 256, 256, 0, stream>>>(dst, src, cursor, eidx, nid, sid);
  k1_qkv<<<(NN + 63) / 64, 256, 0, stream>>>(x, BpQ, qkv_b, Q, Kq, V);
  k2_edge<<<NE / 64, 256, 0, stream>>>(e, eidx, nid, sid, BpE, E_b, Aw, Bp1, conn1_b,
                                       Q, Kq, ln1c_g, ln1c_b, Bp2, conn2_b,
                                       ln2c_g, ln2c_b, cmb, sexp, out_conn);
  k_agg<<<(NN * 64 + 255) / 256, 256, 0, stream>>>(startp, sid, sexp, cmb, V, x, hpre);
  k5_node<<<(NN + 63) / 64, 256, 0, stream>>>(hpre, ln1h_g, ln1h_b, BpF1, ffn1_b,
                                              BpF2, ffn2_b, ln2h_g, ln2h_b, out_h);
}

// Round 10
// 535.071 us; speedup vs baseline: 2.9199x; 1.1731x over previous
//
#include <hip/hip_runtime.h>
#include <cstdint>

#define NN 50000
#define NE 512000

typedef unsigned short bf16u;
typedef __attribute__((ext_vector_type(8))) short short8v;
typedef __attribute__((ext_vector_type(4))) float f32x4;

__device__ __forceinline__ bf16u f2bf(float f){
  union { float f; unsigned int u; } v; v.f = f;
  unsigned int r = v.u + 0x7FFFu + ((v.u >> 16) & 1u);
  return (bf16u)(r >> 16);
}
__device__ __forceinline__ float bf2f(bf16u s){
  union { unsigned int u; float f; } v; v.u = ((unsigned int)s) << 16;
  return v.f;
}

// ---------- K0: weight packing into MFMA B-fragments ----------
// B-frag layout (mfma_f32_16x16x32_bf16): elem [((ks*NF+nf)*64+l)*8+j] =
//   W[n][k],  n = nf*16 + (l&15),  k = ks*32 + ((l>>4)<<3) + j
__global__ void k0_pack(const float* __restrict__ E_w, const float* __restrict__ conn1_w,
                        const float* __restrict__ conn2_w, const float* __restrict__ qkv_w,
                        const float* __restrict__ ffn1_w, const float* __restrict__ ffn2_w,
                        bf16u* __restrict__ BpE, bf16u* __restrict__ Bp1,
                        bf16u* __restrict__ Bp2, bf16u* __restrict__ BpQ,
                        bf16u* __restrict__ BpF1, bf16u* __restrict__ BpF2){
  int i = blockIdx.x * 256 + threadIdx.x;   // 0..12287
  int j = i & 7, l = (i >> 3) & 63;
  int nl = l & 15, kl = (l >> 4) << 3;
  if (i < 8192){   // E_w: (128,64), NF=8, KS=2
    int rest = i >> 9, nf = rest & 7, ks = rest >> 3;
    int n = nf * 16 + nl, k = ks * 32 + kl + j;
    BpE[i] = f2bf(E_w[n * 64 + k]);
  }
  if (i < 4096){   // conn1_w/conn2_w: (64,64), NF=4, KS=2
    int rest = i >> 9, nf = rest & 3, ks = rest >> 2;
    int n = nf * 16 + nl, k = ks * 32 + kl + j;
    Bp1[i] = f2bf(conn1_w[n * 64 + k]);
    Bp2[i] = f2bf(conn2_w[n * 64 + k]);
  }
  if (i < 12288){  // qkv_w: (192,64), NF=12, KS=2
    int rest = i >> 9, nf = rest % 12, ks = rest / 12;
    int n = nf * 16 + nl, k = ks * 32 + kl + j;
    BpQ[i] = f2bf(qkv_w[n * 64 + k]);
  }
  if (i < 8192){   // ffn1_w: (128,64), NF=8, KS=2
    int rest = i >> 9, nf = rest & 7, ks = rest >> 3;
    int n = nf * 16 + nl, k = ks * 32 + kl + j;
    BpF1[i] = f2bf(ffn1_w[n * 64 + k]);
  }
  if (i < 8192){   // ffn2_w: (64,128), NF=4, KS=4
    int rest = i >> 9, nf = rest & 3, ks = rest >> 2;
    int n = nf * 16 + nl, k = ks * 32 + kl + j;
    BpF2[i] = f2bf(ffn2_w[n * 128 + k]);
  }
}

// ---------- CSR build ----------
__global__ void k_hist(const int* __restrict__ dst, int* __restrict__ cnt){
  int e = blockIdx.x * 256 + threadIdx.x;
  if (e < NE) atomicAdd(&cnt[dst[e]], 1);
}

#define SCAN_T 1024
#define PER_T 49
__global__ __launch_bounds__(SCAN_T) void k_scan(const int* __restrict__ cnt,
                                                 int* __restrict__ start, int* __restrict__ cursor){
  __shared__ int ls[SCAN_T];
  int t = threadIdx.x;
  int base = t * PER_T;
  int s = 0;
  for (int i = 0; i < PER_T; ++i){ int n = base + i; if (n < NN) s += cnt[n]; }
  ls[t] = s; __syncthreads();
  for (int off = 1; off < SCAN_T; off <<= 1){
    int v = ls[t];
    int add = (t >= off) ? ls[t - off] : 0;
    __syncthreads();
    ls[t] = v + add;
    __syncthreads();
  }
  int run = (t > 0) ? ls[t - 1] : 0;
  for (int i = 0; i < PER_T; ++i){
    int n = base + i;
    if (n < NN){ start[n] = run; cursor[n] = run; run += cnt[n]; }
  }
  if (t == SCAN_T - 1) start[NN] = run;
}

__global__ void k_scatter(const int* __restrict__ dst, const int* __restrict__ src,
                          int* __restrict__ cursor, int* __restrict__ eidx,
                          int* __restrict__ nid, int* __restrict__ sid){
  int e = blockIdx.x * 256 + threadIdx.x;
  if (e < NE){
    int dn = dst[e];
    int p = atomicAdd(&cursor[dn], 1);
    eidx[p] = e;
    nid[p] = dn;
    sid[p] = src[e];
  }
}

// ---------- K1: node QKV — MFMA, split-bf16 A ----------
__global__ __launch_bounds__(256) void k1_qkv(const float* __restrict__ x,
    const bf16u* __restrict__ BpQ, const float* __restrict__ qkv_b,
    float* __restrict__ Q, float* __restrict__ K, float* __restrict__ V){
  int tile = blockIdx.x * 64;
  int w = threadIdx.x >> 6, l = threadIdx.x & 63;
  int lg = l >> 4, li = l & 15;
  const short8v* bpq = (const short8v*)BpQ;
  short8v Bq[3][2];
#pragma unroll
  for (int p = 0; p < 3; ++p)
#pragma unroll
    for (int ks = 0; ks < 2; ++ks)
      Bq[p][ks] = bpq[(ks * 12 + p * 4 + w) * 64 + l];
  f32x4 z = {0.f, 0.f, 0.f, 0.f};
  f32x4 acc[3][4];
#pragma unroll
  for (int p = 0; p < 3; ++p)
#pragma unroll
    for (int mf = 0; mf < 4; ++mf) acc[p][mf] = z;
#pragma unroll
  for (int mf = 0; mf < 4; ++mf){
    int row = tile + mf * 16 + li;
    bool g = row < NN;
    const float* xp = x + (size_t)row * 64 + lg * 8;
#pragma unroll
    for (int ks = 0; ks < 2; ++ks){
      float v[8];
      if (g){
        float4 t0 = *(const float4*)(xp + ks * 32);
        float4 t1 = *(const float4*)(xp + ks * 32 + 4);
        v[0]=t0.x; v[1]=t0.y; v[2]=t0.z; v[3]=t0.w;
        v[4]=t1.x; v[5]=t1.y; v[6]=t1.z; v[7]=t1.w;
      } else {
#pragma unroll
        for (int j = 0; j < 8; ++j) v[j] = 0.f;
      }
      short8v hi, lo;
#pragma unroll
      for (int j = 0; j < 8; ++j){
        bf16u h = f2bf(v[j]);
        hi[j] = (short)h;
        lo[j] = (short)f2bf(v[j] - bf2f(h));
      }
#pragma unroll
      for (int p = 0; p < 3; ++p){
        acc[p][mf] = __builtin_amdgcn_mfma_f32_16x16x32_bf16(hi, Bq[p][ks], acc[p][mf], 0, 0, 0);
        acc[p][mf] = __builtin_amdgcn_mfma_f32_16x16x32_bf16(lo, Bq[p][ks], acc[p][mf], 0, 0, 0);
      }
    }
  }
  float bias[3] = {qkv_b[w*16+li], qkv_b[64+w*16+li], qkv_b[128+w*16+li]};
  float* outs[3] = {Q, K, V};
#pragma unroll
  for (int p = 0; p < 3; ++p)
#pragma unroll
    for (int mf = 0; mf < 4; ++mf)
#pragma unroll
      for (int r = 0; r < 4; ++r){
        int row = tile + mf * 16 + lg * 4 + r;
        if (row < NN) outs[p][(size_t)row * 64 + w * 16 + li] = acc[p][mf][r] + bias[p];
      }
}

// ---------- K2: fused edge kernel — LDS-phase LN reductions ----------
__global__ __launch_bounds__(256, 6) void k2_edge(
    const float* __restrict__ e, const int* __restrict__ eidx,
    const int* __restrict__ nid, const int* __restrict__ sid,
    const bf16u* __restrict__ BpE, const float* __restrict__ E_b,
    const float* __restrict__ Aw, const bf16u* __restrict__ Bp1, const float* __restrict__ conn1_b,
    const float* __restrict__ Q, const float* __restrict__ K,
    const float* __restrict__ g1c, const float* __restrict__ b1c,
    const bf16u* __restrict__ Bp2, const float* __restrict__ conn2_b,
    const float* __restrict__ g2c, const float* __restrict__ b2c,
    bf16u* __restrict__ cm, float* __restrict__ sexp, float* __restrict__ out_conn){
  __shared__ bf16u cpre[64 * 72];
  __shared__ float shbuf[64 * 68];   // phase B/C: cmid (bf16); phase D/E: rbuf (f32)
  __shared__ float mu1[64], rs1[64], mu2[64], rs2[64];
  bf16u* cmid = (bf16u*)shbuf;
  float* rbuf = shbuf;
  int tile = blockIdx.x * 64;
  int t = threadIdx.x;
  int w = t >> 6, l = t & 63;
  int lg = l >> 4, li = l & 15;
  int dloc = w * 16 + li;

  float eb0 = E_b[dloc], eb1 = E_b[64 + dloc];
  float awv = Aw[li * 4 + w];
  f32x4 z = {0.f, 0.f, 0.f, 0.f};

  // --- phase A: per-mf Eh MFMA + pointwise (score shfl kept: 4/iter) ---
  {
    const short8v* bpe = (const short8v*)BpE;
    short8v BW0 = bpe[(0*8 + w)     * 64 + l];
    short8v BW1 = bpe[(1*8 + w)     * 64 + l];
    short8v BB0 = bpe[(0*8 + 4 + w) * 64 + l];
    short8v BB1 = bpe[(1*8 + 4 + w) * 64 + l];
#pragma unroll
    for (int mf = 0; mf < 4; ++mf){
      int eidA = eidx[tile + mf * 16 + li];
      const float* ep = e + (size_t)eidA * 64 + lg * 8;
      f32x4 accW = z, accB = z;
#pragma unroll
      for (int ks = 0; ks < 2; ++ks){
        float4 a0 = *(const float4*)(ep + ks * 32);
        float4 a1 = *(const float4*)(ep + ks * 32 + 4);
        short8v af;
        af[0]=(short)f2bf(a0.x); af[1]=(short)f2bf(a0.y); af[2]=(short)f2bf(a0.z); af[3]=(short)f2bf(a0.w);
        af[4]=(short)f2bf(a1.x); af[5]=(short)f2bf(a1.y); af[6]=(short)f2bf(a1.z); af[7]=(short)f2bf(a1.w);
        accW = __builtin_amdgcn_mfma_f32_16x16x32_bf16(af, ks ? BW1 : BW0, accW, 0, 0, 0);
        accB = __builtin_amdgcn_mfma_f32_16x16x32_bf16(af, ks ? BB1 : BB0, accB, 0, 0, 0);
      }
#pragma unroll
      for (int r = 0; r < 4; ++r){
        int el = mf * 16 + lg * 4 + r;
        int pos = tile + el;
        int dn = nid[pos], sn = sid[pos];
        float qv = Q[(size_t)dn * 64 + dloc];
        float kv = K[(size_t)sn * 64 + dloc];
        float ew  = accW[r] + eb0;
        float ebv = accB[r] + eb1;
        float c1 = (qv + kv) * ew;
        float c2 = copysignf(sqrtf(fabsf(c1)), c1);
        float cpv = fmaxf(c2 + ebv, 0.f);
        float s = cpv * awv;
        s += __shfl_xor(s, 1); s += __shfl_xor(s, 2);
        s += __shfl_xor(s, 4); s += __shfl_xor(s, 8);
        if (li == 0){
          float sc = fminf(fmaxf(s, -5.f), 5.f);
          sexp[(size_t)pos * 4 + w] = __expf(sc);
        }
        cpre[el * 72 + dloc] = f2bf(cpv);
      }
    }
  }
  __syncthreads();

  // --- phase B: conn1 MFMA; store cm global + cmid LDS (no stats) ---
  {
    float c1b = conn1_b[dloc];
    const short8v* bp1 = (const short8v*)Bp1;
    short8v B10 = bp1[(0*4 + w) * 64 + l];
    short8v B11 = bp1[(1*4 + w) * 64 + l];
#pragma unroll
    for (int mf = 0; mf < 4; ++mf){
      const bf16u* ap = &cpre[(mf * 16 + li) * 72 + lg * 8];
      short8v a0 = *(const short8v*)(ap);
      short8v a1 = *(const short8v*)(ap + 32);
      f32x4 acc = z;
      acc = __builtin_amdgcn_mfma_f32_16x16x32_bf16(a0, B10, acc, 0, 0, 0);
      acc = __builtin_amdgcn_mfma_f32_16x16x32_bf16(a1, B11, acc, 0, 0, 0);
#pragma unroll
      for (int r = 0; r < 4; ++r){
        int el = mf * 16 + lg * 4 + r;
        bf16u vb = f2bf(acc[r] + c1b);
        cm[(size_t)(tile + el) * 64 + dloc] = vb;
        cmid[el * 72 + dloc] = vb;
      }
    }
  }
  __syncthreads();

  // --- phase B2: LN1c stats from cmid, thread = (row, quarter) ---
  {
    int el = t >> 2, q = t & 3;
    const short8v* cp8 = (const short8v*)&cmid[el * 72 + q * 16];
    short8v c0 = cp8[0], c1 = cp8[1];
    float s = 0.f, sq = 0.f;
#pragma unroll
    for (int i = 0; i < 8; ++i){
      float v0 = bf2f((bf16u)c0[i]), v1 = bf2f((bf16u)c1[i]);
      s += v0 + v1; sq += v0*v0 + v1*v1;
    }
    s  += __shfl_xor(s, 1);  s  += __shfl_xor(s, 2);
    sq += __shfl_xor(sq, 1); sq += __shfl_xor(sq, 2);
    if (q == 0){
      float mu = s * (1.f/64.f);
      float var = sq * (1.f/64.f) - mu * mu;
      mu1[el] = mu;
      rs1[el] = rsqrtf(fmaxf(var, 0.f) + 1e-5f);
    }
  }
  __syncthreads();

  // --- phase C: LN1c normalize + relu -> cpre (overwrite) ---
  {
    float g1v = g1c[dloc], b1v = b1c[dloc];
#pragma unroll
    for (int mf = 0; mf < 4; ++mf){
#pragma unroll
      for (int r = 0; r < 4; ++r){
        int el = mf * 16 + lg * 4 + r;
        float cv = bf2f(cmid[el * 72 + dloc]);
        float cn = fmaxf((cv - mu1[el]) * rs1[el] * g1v + b1v, 0.f);
        cpre[el * 72 + dloc] = f2bf(cn);
      }
    }
  }
  __syncthreads();   // cpre rewritten AND cmid's storage about to be reused as rbuf

  // --- phase D: conn2 MFMA + residual -> rbuf (f32, overlays cmid) ---
  {
    float c2b = conn2_b[dloc];
    const short8v* bp2 = (const short8v*)Bp2;
    short8v B20 = bp2[(0*4 + w) * 64 + l];
    short8v B21 = bp2[(1*4 + w) * 64 + l];
#pragma unroll
    for (int mf = 0; mf < 4; ++mf){
      const bf16u* ap = &cpre[(mf * 16 + li) * 72 + lg * 8];
      short8v a0 = *(const short8v*)(ap);
      short8v a1 = *(const short8v*)(ap + 32);
      f32x4 acc = z;
      acc = __builtin_amdgcn_mfma_f32_16x16x32_bf16(a0, B20, acc, 0, 0, 0);
      acc = __builtin_amdgcn_mfma_f32_16x16x32_bf16(a1, B21, acc, 0, 0, 0);
#pragma unroll
      for (int r = 0; r < 4; ++r){
        int el = mf * 16 + lg * 4 + r;
        int eid = eidx[tile + el];
        rbuf[el * 68 + dloc] = acc[r] + c2b + e[(size_t)eid * 64 + dloc];
      }
    }
  }
  __syncthreads();

  // --- phase D2: LN2c stats from rbuf ---
  {
    int el = t >> 2, q = t & 3;
    const float4* rp = (const float4*)&rbuf[el * 68 + q * 16];
    float s = 0.f, sq = 0.f;
#pragma unroll
    for (int c = 0; c < 4; ++c){
      float4 v = rp[c];
      s  += v.x + v.y + v.z + v.w;
      sq += v.x*v.x + v.y*v.y + v.z*v.z + v.w*v.w;
    }
    s  += __shfl_xor(s, 1);  s  += __shfl_xor(s, 2);
    sq += __shfl_xor(sq, 1); sq += __shfl_xor(sq, 2);
    if (q == 0){
      float mu = s * (1.f/64.f);
      float var = sq * (1.f/64.f) - mu * mu;
      mu2[el] = mu;
      rs2[el] = rsqrtf(fmaxf(var, 0.f) + 1e-5f);
    }
  }
  __syncthreads();

  // --- phase E: LN2c + scatter store by eid ---
  {
    float g2v = g2c[dloc], b2v = b2c[dloc];
#pragma unroll
    for (int mf = 0; mf < 4; ++mf){
#pragma unroll
      for (int r = 0; r < 4; ++r){
        int el = mf * 16 + lg * 4 + r;
        int eid = eidx[tile + el];
        float rv = rbuf[el * 68 + dloc];
        out_conn[(size_t)eid * 64 + dloc] = (rv - mu2[el]) * rs2[el] * g2v + b2v;
      }
    }
  }
}

// ---------- K_agg: wave per node; cm/sexp sequential, V gathered ----------
__global__ __launch_bounds__(256) void k_agg(
    const int* __restrict__ start, const int* __restrict__ sid,
    const float* __restrict__ sexp, const bf16u* __restrict__ cm, const float* __restrict__ V,
    const float* __restrict__ x, float* __restrict__ hpre){
  int wid = (blockIdx.x * 256 + threadIdx.x) >> 6;
  int lane = threadIdx.x & 63;
  if (wid >= NN) return;
  int s0 = start[wid], s1 = start[wid + 1];
  int h = lane >> 4;
  float num = 0.f, den = 0.f;
  for (int i = s0; i < s1; ++i){
    float sx = sexp[(size_t)i * 4 + h];
    int sn = sid[i];
    float v  = V[(size_t)sn * 64 + lane];
    float cc = bf2f(cm[(size_t)i * 64 + lane]);
    num += sx * (v + cc);
    den += sx;
  }
  hpre[(size_t)wid * 64 + lane] = x[(size_t)wid * 64 + lane] + num / (den + 1e-16f);
}

// ---------- K5: node final — LN1h + FFN (MFMA) + LN2h ----------
__global__ __launch_bounds__(256) void k5_node(
    const float* __restrict__ hpre,
    const float* __restrict__ g1, const float* __restrict__ b1,
    const bf16u* __restrict__ BpF1, const float* __restrict__ ffn1_b,
    const bf16u* __restrict__ BpF2, const float* __restrict__ ffn2_b,
    const float* __restrict__ g2, const float* __restrict__ b2,
    float* __restrict__ out_h){
  __shared__ bf16u hlhi[64 * 72];
  __shared__ bf16u hllo[64 * 72];
  __shared__ bf16u g1o[64 * 136];
  __shared__ float reds[64][4];
  __shared__ float redq[64][4];
  int tile = blockIdx.x * 64;
  int t = threadIdx.x;
  {
    int el = t >> 2, q = t & 3;
    int row = tile + el;
    bool g = row < NN;
    float v[16];
    if (g){
      const float4* hp = (const float4*)(hpre + (size_t)row * 64 + q * 16);
#pragma unroll
      for (int c = 0; c < 4; ++c){
        float4 tv = hp[c];
        v[c*4+0]=tv.x; v[c*4+1]=tv.y; v[c*4+2]=tv.z; v[c*4+3]=tv.w;
      }
    } else {
#pragma unroll
      for (int i = 0; i < 16; ++i) v[i] = 0.f;
    }
    float s = 0.f, sq = 0.f;
#pragma unroll
    for (int i = 0; i < 16; ++i){ s += v[i]; sq += v[i]*v[i]; }
    s  += __shfl_xor(s, 1);  s  += __shfl_xor(s, 2);
    sq += __shfl_xor(sq, 1); sq += __shfl_xor(sq, 2);
    float mu = s * (1.f/64.f);
    float var = sq * (1.f/64.f) - mu * mu;
    float rs = rsqrtf(fmaxf(var, 0.f) + 1e-5f);
#pragma unroll
    for (int i = 0; i < 16; ++i){
      int d = q * 16 + i;
      float hv = (v[i] - mu) * rs * g1[d] + b1[d];
      bf16u hb = f2bf(hv);
      hlhi[el * 72 + d] = hb;
      hllo[el * 72 + d] = f2bf(hv - bf2f(hb));
    }
  }
  __syncthreads();
  int w = t >> 6, l = t & 63;
  int lg = l >> 4, li = l & 15;
  const short8v* bpf1 = (const short8v*)BpF1;
  short8v B1f[2][2];
#pragma unroll
  for (int f = 0; f < 2; ++f)
#pragma unroll
    for (int ks = 0; ks < 2; ++ks)
      B1f[f][ks] = bpf1[(ks * 8 + f * 4 + w) * 64 + l];
  f32x4 z = {0.f, 0.f, 0.f, 0.f};
  f32x4 acc1[2][4];
#pragma unroll
  for (int f = 0; f < 2; ++f)
#pragma unroll
    for (int mf = 0; mf < 4; ++mf) acc1[f][mf] = z;
#pragma unroll
  for (int mf = 0; mf < 4; ++mf){
#pragma unroll
    for (int ks = 0; ks < 2; ++ks){
      const bf16u* ah = &hlhi[(mf * 16 + li) * 72 + ks * 32 + lg * 8];
      const bf16u* al = &hllo[(mf * 16 + li) * 72 + ks * 32 + lg * 8];
      short8v Ahi = *(const short8v*)ah;
      short8v Alo = *(const short8v*)al;
#pragma unroll
      for (int f = 0; f < 2; ++f){
        acc1[f][mf] = __builtin_amdgcn_mfma_f32_16x16x32_bf16(Ahi, B1f[f][ks], acc1[f][mf], 0, 0, 0);
        acc1[f][mf] = __builtin_amdgcn_mfma_f32_16x16x32_bf16(Alo, B1f[f][ks], acc1[f][mf], 0, 0, 0);
      }
    }
  }
  float fb[2] = {ffn1_b[w*16+li], ffn1_b[64+w*16+li]};
#pragma unroll
  for (int f = 0; f < 2; ++f)
#pragma unroll
    for (int mf = 0; mf < 4; ++mf)
#pragma unroll
      for (int r = 0; r < 4; ++r){
        int rowl = mf * 16 + lg * 4 + r;
        int col = f * 64 + w * 16 + li;
        g1o[rowl * 136 + col] = f2bf(fmaxf(acc1[f][mf][r] + fb[f], 0.f));
      }
  __syncthreads();
  const short8v* bpf2 = (const short8v*)BpF2;
  short8v B2f[4];
#pragma unroll
  for (int ks = 0; ks < 4; ++ks) B2f[ks] = bpf2[(ks * 4 + w) * 64 + l];
  int o = w * 16 + li;
  float f2b_ = ffn2_b[o];
  float racc[4][4];
#pragma unroll
  for (int mf = 0; mf < 4; ++mf){
    f32x4 acc = z;
#pragma unroll
    for (int ks = 0; ks < 4; ++ks){
      short8v A2 = *(const short8v*)&g1o[(mf * 16 + li) * 136 + ks * 32 + lg * 8];
      acc = __builtin_amdgcn_mfma_f32_16x16x32_bf16(A2, B2f[ks], acc, 0, 0, 0);
    }
#pragma unroll
    for (int r = 0; r < 4; ++r){
      int rowl = mf * 16 + lg * 4 + r;
      int row = tile + rowl;
      float hres = (row < NN) ? hpre[(size_t)row * 64 + o] : 0.f;
      float rv = acc[r] + f2b_ + hres;
      racc[mf][r] = rv;
      float s = rv, q2 = rv * rv;
      s  += __shfl_xor(s, 1);  s  += __shfl_xor(s, 2);  s  += __shfl_xor(s, 4);  s  += __shfl_xor(s, 8);
      q2 += __shfl_xor(q2, 1); q2 += __shfl_xor(q2, 2); q2 += __shfl_xor(q2, 4); q2 += __shfl_xor(q2, 8);
      if (li == 0){ reds[rowl][w] = s; redq[rowl][w] = q2; }
    }
  }
  __syncthreads();
  float g2v = g2[o], b2v = b2[o];
#pragma unroll
  for (int mf = 0; mf < 4; ++mf){
#pragma unroll
    for (int r = 0; r < 4; ++r){
      int rowl = mf * 16 + lg * 4 + r;
      int row = tile + rowl;
      if (row < NN){
        float S  = reds[rowl][0] + reds[rowl][1] + reds[rowl][2] + reds[rowl][3];
        float Qq = redq[rowl][0] + redq[rowl][1] + redq[rowl][2] + redq[rowl][3];
        float mu2 = S * (1.f/64.f);
        float var2 = Qq * (1.f/64.f) - mu2 * mu2;
        float rs2 = rsqrtf(fmaxf(var2, 0.f) + 1e-5f);
        out_h[(size_t)row * 64 + o] = (racc[mf][r] - mu2) * rs2 * g2v + b2v;
      }
    }
  }
}

extern "C" void kernel_launch(void* const* d_in, const int* in_sizes, int n_in,
                              void* d_out, int out_size, void* d_ws, size_t ws_size,
                              hipStream_t stream){
  const float* x       = (const float*)d_in[0];
  const float* e       = (const float*)d_in[1];
  const int*   dst     = (const int*)d_in[2];
  const int*   src     = (const int*)d_in[3];
  const float* qkv_w   = (const float*)d_in[4];
  const float* qkv_b   = (const float*)d_in[5];
  const float* E_w     = (const float*)d_in[6];
  const float* E_b     = (const float*)d_in[7];
  const float* Aw      = (const float*)d_in[8];
  const float* conn1_w = (const float*)d_in[9];
  const float* conn1_b = (const float*)d_in[10];
  const float* conn2_w = (const float*)d_in[11];
  const float* conn2_b = (const float*)d_in[12];
  const float* ffn1_w  = (const float*)d_in[13];
  const float* ffn1_b  = (const float*)d_in[14];
  const float* ffn2_w  = (const float*)d_in[15];
  const float* ffn2_b  = (const float*)d_in[16];
  const float* ln1h_g  = (const float*)d_in[17];
  const float* ln1h_b  = (const float*)d_in[18];
  const float* ln2h_g  = (const float*)d_in[19];
  const float* ln2h_b  = (const float*)d_in[20];
  const float* ln1c_g  = (const float*)d_in[21];
  const float* ln1c_b  = (const float*)d_in[22];
  const float* ln2c_g  = (const float*)d_in[23];
  const float* ln2c_b  = (const float*)d_in[24];

  char* ws = (char*)d_ws;
  size_t off = 0;
  auto alloc = [&](size_t bytes) -> void* {
    void* p = ws + off;
    off += (bytes + 255) & ~(size_t)255;
    return p;
  };
  float* Q     = (float*)alloc((size_t)NN * 64 * 4);
  float* Kq    = (float*)alloc((size_t)NN * 64 * 4);
  float* V     = (float*)alloc((size_t)NN * 64 * 4);
  bf16u* cmb   = (bf16u*)alloc((size_t)NE * 64 * 2);
  float* sexp  = (float*)alloc((size_t)NE * 4 * 4);
  float* hpre  = (float*)alloc((size_t)NN * 64 * 4);
  bf16u* BpE   = (bf16u*)alloc(8192 * 2);
  bf16u* Bp1   = (bf16u*)alloc(4096 * 2);
  bf16u* Bp2   = (bf16u*)alloc(4096 * 2);
  bf16u* BpQ   = (bf16u*)alloc(12288 * 2);
  bf16u* BpF1  = (bf16u*)alloc(8192 * 2);
  bf16u* BpF2  = (bf16u*)alloc(8192 * 2);
  int*   cnt   = (int*)alloc((size_t)NN * 4);
  int*   startp= (int*)alloc(((size_t)NN + 1) * 4);
  int*   cursor= (int*)alloc((size_t)NN * 4);
  int*   eidx  = (int*)alloc((size_t)NE * 4);
  int*   nid   = (int*)alloc((size_t)NE * 4);
  int*   sid   = (int*)alloc((size_t)NE * 4);

  float* out_h    = (float*)d_out;
  float* out_conn = out_h + (size_t)NN * 64;

  hipMemsetAsync(cnt, 0, (size_t)NN * 4, stream);

  k0_pack<<<48, 256, 0, stream>>>(E_w, conn1_w, conn2_w, qkv_w, ffn1_w, ffn2_w,
                                  BpE, Bp1, Bp2, BpQ, BpF1, BpF2);
  k_hist<<<NE / 256, 256, 0, stream>>>(dst, cnt);
  k_scan<<<1, SCAN_T, 0, stream>>>(cnt, startp, cursor);
  k_scatter<<<NE / 256, 256, 0, stream>>>(dst, src, cursor, eidx, nid, sid);
  k1_qkv<<<(NN + 63) / 64, 256, 0, stream>>>(x, BpQ, qkv_b, Q, Kq, V);
  k2_edge<<<NE / 64, 256, 0, stream>>>(e, eidx, nid, sid, BpE, E_b, Aw, Bp1, conn1_b,
                                       Q, Kq, ln1c_g, ln1c_b, Bp2, conn2_b,
                                       ln2c_g, ln2c_b, cmb, sexp, out_conn);
  k_agg<<<(NN * 64 + 255) / 256, 256, 0, stream>>>(startp, sid, sexp, cmb, V, x, hpre);
  k5_node<<<(NN + 63) / 64, 256, 0, stream>>>(hpre, ln1h_g, ln1h_b, BpF1, ffn1_b,
                                              BpF2, ffn2_b, ln2h_g, ln2h_b, out_h);
}